// Round 5
// baseline (232.376 us; speedup 1.0000x reference)
//
#include <hip/hip_runtime.h>
#include <stdint.h>

typedef __attribute__((ext_vector_type(8))) short short8;
typedef __attribute__((ext_vector_type(4))) short short4v;
typedef __attribute__((ext_vector_type(4))) float floatx4;

#define QSCALE 0.1803368801111f /* 0.125 * log2(e): S in log2 units */

__device__ __forceinline__ unsigned short f2bf(float f) {
  unsigned int u = __float_as_uint(f);
  unsigned int r = (u + 0x7FFFu + ((u >> 16) & 1u)) >> 16;  // RNE
  return (unsigned short)r;
}

__device__ __forceinline__ unsigned int cvt_pk_bf16(float lo, float hi) {
  unsigned int r;
  asm("v_cvt_pk_bf16_f32 %0, %1, %2" : "=v"(r) : "v"(lo), "v"(hi));
  return r;
}

__device__ __forceinline__ void async_copy16(void* lds, const void* g) {
  __builtin_amdgcn_global_load_lds(
      (const __attribute__((address_space(1))) unsigned int*)g,
      (__attribute__((address_space(3))) unsigned int*)lds, 16, 0, 0);
}

// ---------------------------------------------------------------------------
// fp32 -> bf16 conversion
// ---------------------------------------------------------------------------
__global__ __launch_bounds__(256) void f2b_kernel(const float* __restrict__ in,
                                                  unsigned short* __restrict__ out,
                                                  int n4) {
  int i = blockIdx.x * 256 + threadIdx.x;
  if (i >= n4) return;
  float4 v = ((const float4*)in)[i];
  short4v o;
  o[0] = (short)f2bf(v.x);
  o[1] = (short)f2bf(v.y);
  o[2] = (short)f2bf(v.z);
  o[3] = (short)f2bf(v.w);
  *(short4v*)(out + (long)i * 4) = o;
}

// ===========================================================================
// 8-phase 256x256 GEMM (T2+T3+T4+T5), K=1024, BK=64, 512 threads (8 waves).
// LDS: A[2buf][2half][128][64] + B same = 128 KiB. Half-tile = 128 rows x 64k.
// Per phase (Qm,Qn): barrier -> 12x swizzled ds_read_b128 -> stage one
// half-tile of tile t+1 (2x global_load_lds, pre-swizzled global source) ->
// 16 MFMA (setprio). Counted s_waitcnt vmcnt(4) before phases 1-3 only.
// Stage order per tile: A0,B0,B1,A1; phase consumption A0B0 / A0B1 / A1B0 /
// A1B1 -> every wait retires exactly the half-tile the phase needs.
// ===========================================================================
__device__ __forceinline__ void stage_half_g(const char* __restrict__ gmat,
                                             int grow0, int kbyte,
                                             char* __restrict__ lds_base, int tid) {
  const int wv = tid >> 6;
#pragma unroll
  for (int j = 0; j < 2; ++j) {
    int s = j * 512 + tid;          // chunk-slot 0..1023 (128 rows x 8 chunks)
    int row = s >> 3, cph = s & 7;
    int cl = cph ^ (row & 7);       // pre-swizzled global chunk
    async_copy16(lds_base + (j * 512 + wv * 64) * 16,
                 gmat + (long)(grow0 + row) * 2048 + kbyte + cl * 16);
  }
}

template <int QM, int QN>
__device__ __forceinline__ void gemm_phase(const char* __restrict__ Asl,
                                           const char* __restrict__ Bsl, int buf,
                                           int wm, int wn, int lr, int lg,
                                           floatx4 acc[2][2][4][2]) {
  const char* Ab = Asl + (buf * 2 + QM) * 16384;
  const char* Bb = Bsl + (buf * 2 + QN) * 16384;
  short8 av[4][2], bv[2][2];
#pragma unroll
  for (int m = 0; m < 4; ++m) {
    int R = wm * 64 + m * 16 + lr;
#pragma unroll
    for (int ks = 0; ks < 2; ++ks)
      av[m][ks] = *(const short8*)(Ab + R * 128 + (((ks * 4 + lg) ^ (R & 7)) * 16));
  }
#pragma unroll
  for (int n = 0; n < 2; ++n) {
    int R = wn * 32 + n * 16 + lr;
#pragma unroll
    for (int ks = 0; ks < 2; ++ks)
      bv[n][ks] = *(const short8*)(Bb + R * 128 + (((ks * 4 + lg) ^ (R & 7)) * 16));
  }
  __builtin_amdgcn_s_setprio(1);
#pragma unroll
  for (int m = 0; m < 4; ++m)
#pragma unroll
    for (int n = 0; n < 2; ++n)
#pragma unroll
      for (int ks = 0; ks < 2; ++ks)
        acc[QM][QN][m][n] = __builtin_amdgcn_mfma_f32_16x16x32_bf16(
            av[m][ks], bv[n][ks], acc[QM][QN][m][n], 0, 0, 0);
  __builtin_amdgcn_s_setprio(0);
}

#define PH_SYNC(WAIT)                                    \
  do {                                                   \
    if (WAIT) asm volatile("s_waitcnt vmcnt(4)" ::: "memory"); \
    __builtin_amdgcn_s_barrier();                        \
    __builtin_amdgcn_sched_barrier(0);                   \
  } while (0)

__global__ __launch_bounds__(512, 1) void qkv_gemm8(
    const unsigned short* __restrict__ xb, const unsigned short* __restrict__ wqkv,
    const float* __restrict__ bq, const float* __restrict__ bk,
    const float* __restrict__ bv, unsigned short* __restrict__ q_out,
    unsigned short* __restrict__ k_out, unsigned short* __restrict__ vt_out) {
  __shared__ __align__(16) char Lds[131072];
  char* Asl = Lds;
  char* Bsl = Lds + 65536;
  const char* Ag = (const char*)xb;
  const char* Bg = (const char*)wqkv;

  // XCD-grouped tile mapping (384 blocks, 8 XCDs x 48)
  const int bid = blockIdx.x;
  const int gid = (bid & 7) * 48 + (bid >> 3);
  const int brow = (gid % 32) * 256;
  const int bcol = (gid / 32) * 256;

  const int tid = threadIdx.x;
  const int wv = tid >> 6, lane = tid & 63;
  const int wm = wv >> 2, wn = wv & 3;  // 2 x 4 wave grid
  const int lr = lane & 15, lg = lane >> 4;

  floatx4 acc[2][2][4][2];
#pragma unroll
  for (int a = 0; a < 2; ++a)
#pragma unroll
    for (int b = 0; b < 2; ++b)
#pragma unroll
      for (int m = 0; m < 4; ++m)
#pragma unroll
        for (int n = 0; n < 2; ++n) acc[a][b][m][n] = floatx4{0.f, 0.f, 0.f, 0.f};

  // prologue: tile 0 -> buf 0, order A0,B0,B1,A1 (8 loads/thread in flight)
  stage_half_g(Ag, brow, 0, Asl + 0 * 16384, tid);
  stage_half_g(Bg, bcol, 0, Bsl + 0 * 16384, tid);
  stage_half_g(Bg, bcol + 128, 0, Bsl + 1 * 16384, tid);
  stage_half_g(Ag, brow + 128, 0, Asl + 1 * 16384, tid);

  int buf = 0;
#pragma unroll 1
  for (int t = 0; t < 16; ++t) {
    const int nt = (t + 1) & 15;  // last iter re-stages tile 0 (junk, dead buf)
    const int kb = nt * 128;
    const int nb = buf ^ 1;
    PH_SYNC(1);  // retires A0,B0 of tile t
    stage_half_g(Ag, brow, kb, Asl + (nb * 2 + 0) * 16384, tid);
    gemm_phase<0, 0>(Asl, Bsl, buf, wm, wn, lr, lg, acc);
    PH_SYNC(1);  // retires B1 of tile t
    stage_half_g(Bg, bcol, kb, Bsl + (nb * 2 + 0) * 16384, tid);
    gemm_phase<0, 1>(Asl, Bsl, buf, wm, wn, lr, lg, acc);
    PH_SYNC(1);  // retires A1 of tile t
    stage_half_g(Bg, bcol + 128, kb, Bsl + (nb * 2 + 1) * 16384, tid);
    gemm_phase<1, 0>(Asl, Bsl, buf, wm, wn, lr, lg, acc);
    PH_SYNC(0);  // everything for tile t already resident
    stage_half_g(Ag, brow + 128, kb, Asl + (nb * 2 + 1) * 16384, tid);
    gemm_phase<1, 1>(Asl, Bsl, buf, wm, wn, lr, lg, acc);
    buf = nb;
  }

  // epilogue: bias + scatter (Q pre-scaled to log2 units; V transposed)
  const int kind = bcol >> 10;
  const float* bias = (kind == 0) ? bq : (kind == 1 ? bk : bv);
#pragma unroll
  for (int qm = 0; qm < 2; ++qm)
#pragma unroll
    for (int qn = 0; qn < 2; ++qn)
#pragma unroll
      for (int m = 0; m < 4; ++m)
#pragma unroll
        for (int n = 0; n < 2; ++n)
#pragma unroll
          for (int r = 0; r < 4; ++r) {
            int gm = brow + qm * 128 + wm * 64 + m * 16 + lg * 4 + r;
            int gn = bcol + qn * 128 + wn * 32 + n * 16 + lr;
            int f = gn & 1023;
            float v = acc[qm][qn][m][n][r] + bias[f];
            if (kind == 0) v *= QSCALE;
            unsigned short o = f2bf(v);
            int h = f >> 6, d = f & 63;
            int bb = gm >> 11, tt = gm & 2047;
            long bh = (long)(bb * 16 + h);
            if (kind == 0)
              q_out[(bh * 2048 + tt) * 64 + d] = o;
            else if (kind == 1)
              k_out[(bh * 2048 + tt) * 64 + d] = o;
            else
              vt_out[(bh * 64 + d) * 2048 + tt] = o;
          }
}

// ---------------------------------------------------------------------------
// m97-structure GEMM mainloop (kept for out_gemm)
// ---------------------------------------------------------------------------
__device__ __forceinline__ void gemm128_mainloop(
    const unsigned short* __restrict__ A, const unsigned short* __restrict__ Bt,
    int K, long brow, long bcol, unsigned short* As, unsigned short* Bs,
    floatx4 acc[4][4]) {
  const int tid = threadIdx.x;
  const int wave = tid >> 6;
  const int lane = tid & 63;
  const int wr = wave >> 1, wc = wave & 1;
  const int lr = lane & 15, lg = lane >> 4;

  const unsigned short* ga = A + (brow + (tid >> 2)) * (long)K + (tid & 3) * 8;
  const unsigned short* gb = Bt + (bcol + (tid >> 2)) * (long)K + (tid & 3) * 8;
  unsigned short* lA = As + wave * 512;
  unsigned short* lB = Bs + wave * 512;
  const int a_off = (wr * 64 + lr) * 32 + lg * 8;
  const int b_off = (wc * 64 + lr) * 32 + lg * 8;

  for (int kt = 0; kt < K; kt += 32) {
    __syncthreads();
    async_copy16(lA, ga);
    async_copy16(lA + 2048, ga + (long)64 * K);
    async_copy16(lB, gb);
    async_copy16(lB + 2048, gb + (long)64 * K);
    ga += 32;
    gb += 32;
    __syncthreads();
    short8 af[4], bf[4];
#pragma unroll
    for (int i = 0; i < 4; ++i) {
      af[i] = *(const short8*)(As + a_off + i * 512);
      bf[i] = *(const short8*)(Bs + b_off + i * 512);
    }
#pragma unroll
    for (int i = 0; i < 4; ++i)
#pragma unroll
      for (int j = 0; j < 4; ++j)
        acc[i][j] = __builtin_amdgcn_mfma_f32_16x16x32_bf16(af[i], bf[j], acc[i][j], 0, 0, 0);
  }
}

// ---------------------------------------------------------------------------
// Output projection
// ---------------------------------------------------------------------------
__global__ __launch_bounds__(256) void out_gemm(
    const unsigned short* __restrict__ ob, const unsigned short* __restrict__ wo,
    const float* __restrict__ bo, float* __restrict__ out) {
  __shared__ unsigned short As[128 * 32];
  __shared__ unsigned short Bs[128 * 32];
  floatx4 zero = {0.f, 0.f, 0.f, 0.f};
  floatx4 acc[4][4];
#pragma unroll
  for (int i = 0; i < 4; ++i)
#pragma unroll
    for (int j = 0; j < 4; ++j) acc[i][j] = zero;

  long brow = (long)blockIdx.x * 128;
  long bcol = (long)blockIdx.y * 128;
  gemm128_mainloop(ob, wo, 1024, brow, bcol, As, Bs, acc);

  const int wave = threadIdx.x >> 6, lane = threadIdx.x & 63;
  const int wr = wave >> 1, wc = wave & 1, lr = lane & 15, lg = lane >> 4;
#pragma unroll
  for (int i = 0; i < 4; ++i)
#pragma unroll
    for (int j = 0; j < 4; ++j)
#pragma unroll
      for (int r = 0; r < 4; ++r) {
        int m = (int)brow + wr * 64 + i * 16 + lg * 4 + r;
        int n = (int)bcol + wc * 64 + j * 16 + lr;
        out[(long)m * 1024 + n] = acc[i][j][r] + bo[n];
      }
}

// ---------------------------------------------------------------------------
// Flash attention v4 (unchanged from round 4)
// ---------------------------------------------------------------------------
__device__ __forceinline__ void stage_kv(char* __restrict__ Kb, char* __restrict__ Vb,
                                         const char* __restrict__ Kp,
                                         const char* __restrict__ Vt, int kv0,
                                         int tid) {
  const int wave = tid >> 6;
#pragma unroll
  for (int j = 0; j < 2; ++j) {
    int d = j * 256 + tid;  // chunk id 0..511
    int row = d >> 3, cc = d & 7;
    int gc = cc ^ (row & 7);
    const char* gk = Kp + (size_t)kv0 * 128 + row * 128 + gc * 16;
    async_copy16(Kb + (j * 256 + wave * 64) * 16, gk);
    const char* gv = Vt + (size_t)row * 4096 + (size_t)kv0 * 2 + gc * 16;
    async_copy16(Vb + (j * 256 + wave * 64) * 16, gv);
  }
}

__device__ __forceinline__ void attn_step(
    const char* __restrict__ Kb, const char* __restrict__ Vb,
    char* __restrict__ PTw, const short8& qf0, const short8& qf1,
    int kv0, int q0, int lr, int lg, bool diag,
    float& m_i, float& l_i, floatx4 accO[4]) {
  floatx4 zero = {0.f, 0.f, 0.f, 0.f};
  const int x7 = lr & 7;
  floatx4 s[4];
  __builtin_amdgcn_s_setprio(1);
#pragma unroll
  for (int nt = 0; nt < 4; ++nt) {
    const char* kr = Kb + (nt * 16 + lr) * 128;
    short8 kf0 = *(const short8*)(kr + ((lg ^ x7) * 16));
    short8 kf1 = *(const short8*)(kr + (((4 + lg) ^ x7) * 16));
    floatx4 a = zero;
    a = __builtin_amdgcn_mfma_f32_16x16x32_bf16(kf0, qf0, a, 0, 0, 0);
    a = __builtin_amdgcn_mfma_f32_16x16x32_bf16(kf1, qf1, a, 0, 0, 0);
    s[nt] = a;
  }
  __builtin_amdgcn_s_setprio(0);

  if (diag) {
    const int q = q0 + lr;
#pragma unroll
    for (int nt = 0; nt < 4; ++nt)
#pragma unroll
      for (int r = 0; r < 4; ++r) {
        int kvi = kv0 + nt * 16 + lg * 4 + r;
        if (kvi > q) s[nt][r] = -1e30f;
      }
  }
  float mnt[4];
#pragma unroll
  for (int nt = 0; nt < 4; ++nt)
    mnt[nt] = fmaxf(fmaxf(s[nt][0], s[nt][1]), fmaxf(s[nt][2], s[nt][3]));
  float pmax = fmaxf(fmaxf(mnt[0], mnt[1]), fmaxf(mnt[2], mnt[3]));

  if (__any(pmax > m_i + 11.5f)) {
    float mx = fmaxf(pmax, __shfl_xor(pmax, 16));
    mx = fmaxf(mx, __shfl_xor(mx, 32));
    float mnew = fmaxf(m_i, mx);
    float scl = exp2f(m_i - mnew);
    m_i = mnew;
    l_i *= scl;
#pragma unroll
    for (int r = 0; r < 4; ++r) {
      float so = __shfl(scl, lg * 4 + r);
#pragma unroll
      for (int dt = 0; dt < 4; ++dt) accO[dt][r] *= so;
    }
  }

#pragma unroll
  for (int nt = 0; nt < 4; ++nt) {
    float p0 = exp2f(s[nt][0] - m_i);
    float p1 = exp2f(s[nt][1] - m_i);
    float p2 = exp2f(s[nt][2] - m_i);
    float p3 = exp2f(s[nt][3] - m_i);
    l_i += (p0 + p1) + (p2 + p3);
    uint2 wv;
    wv.x = cvt_pk_bf16(p0, p1);
    wv.y = cvt_pk_bf16(p2, p3);
    *(uint2*)(PTw + lr * 128 + (((2 * nt + (lg >> 1)) ^ x7) * 16) + ((2 * lg) & 3) * 4) = wv;
  }

  __builtin_amdgcn_s_setprio(1);
#pragma unroll
  for (int kk = 0; kk < 2; ++kk) {
    short8 pf = *(const short8*)(PTw + lr * 128 + (((4 * kk + lg) ^ x7) * 16));
#pragma unroll
    for (int dt = 0; dt < 4; ++dt) {
      short8 vf = *(const short8*)(Vb + (dt * 16 + lr) * 128 + (((4 * kk + lg) ^ x7) * 16));
      accO[dt] = __builtin_amdgcn_mfma_f32_16x16x32_bf16(pf, vf, accO[dt], 0, 0, 0);
    }
  }
  __builtin_amdgcn_s_setprio(0);
}

__global__ __launch_bounds__(256, 4) void attn_fwd(
    const unsigned short* __restrict__ qb, const unsigned short* __restrict__ kb,
    const unsigned short* __restrict__ vtb, unsigned short* __restrict__ ob) {
  __shared__ __align__(16) char Kbuf[2][8192];
  __shared__ __align__(16) char Vbuf[2][8192];
  __shared__ __align__(16) char PTbuf[4][2048];

  const int F = blockIdx.y * 16 + blockIdx.x;  // 0..1023
  const int c = F & 7, t = F >> 3;
  const int bh = c * 8 + (t >> 4);
  const int pr = t & 15;

  const int tid = threadIdx.x;
  const int wave = tid >> 6, lane = tid & 63;
  const int lr = lane & 15, lg = lane >> 4;
  const unsigned short* Q = qb + (long)bh * 2048 * 64;
  const char* Kp = (const char*)(kb + (long)bh * 2048 * 64);
  const char* Vt = (const char*)(vtb + (long)bh * 64 * 2048);
  const int b = bh >> 4, h = bh & 15;
  char* PTw = PTbuf[wave];

  floatx4 zero = {0.f, 0.f, 0.f, 0.f};

#pragma unroll 1
  for (int half = 0; half < 2; ++half) {
    const int qt = half ? (31 - pr) : pr;
    const int q0 = qt * 64 + wave * 16;
    const int nkv = qt + 1;

    short8 qf0 = *(const short8*)(Q + (q0 + lr) * 64 + lg * 8);
    short8 qf1 = *(const short8*)(Q + (q0 + lr) * 64 + 32 + lg * 8);

    floatx4 accO[4];
#pragma unroll
    for (int dt = 0; dt < 4; ++dt) accO[dt] = zero;
    float m_i = -1e30f, l_i = 0.f;

    stage_kv(Kbuf[0], Vbuf[0], Kp, Vt, 0, tid);
    __syncthreads();
#pragma unroll 1
    for (int kv = 0; kv < nkv; ++kv) {
      if (kv + 1 < nkv)
        stage_kv(Kbuf[(kv + 1) & 1], Vbuf[(kv + 1) & 1], Kp, Vt, (kv + 1) * 64, tid);
      attn_step(Kbuf[kv & 1], Vbuf[kv & 1], PTw, qf0, qf1, kv * 64, q0, lr, lg,
                kv == qt, m_i, l_i, accO);
      __syncthreads();
    }

    float lt = l_i + __shfl_xor(l_i, 16);
    lt += __shfl_xor(lt, 32);
    float linv = 1.f / lt;
#pragma unroll
    for (int r = 0; r < 4; ++r) {
      float io = __shfl(linv, lg * 4 + r);
      int tq = q0 + 4 * lg + r;
#pragma unroll
      for (int dt = 0; dt < 4; ++dt)
        ob[((long)b * 2048 + tq) * 1024 + h * 64 + dt * 16 + lr] =
            f2bf(accO[dt][r] * io);
    }
  }
}

// ---------------------------------------------------------------------------
extern "C" void kernel_launch(void* const* d_in, const int* in_sizes, int n_in,
                              void* d_out, int out_size, void* d_ws, size_t ws_size,
                              hipStream_t stream) {
  const float* x = (const float*)d_in[0];
  const float* bq = (const float*)d_in[2];
  const float* bk = (const float*)d_in[4];
  const float* bv = (const float*)d_in[6];
  const float* bo = (const float*)d_in[8];
  float* out = (float*)d_out;

  char* ws = (char*)d_ws;
  unsigned short* xb = (unsigned short*)(ws);                  // 16 MB  [8192][1024]
  unsigned short* wqkv = (unsigned short*)(ws + (16l << 20));  // 6 MB   [3072][1024]
  unsigned short* wob = (unsigned short*)(ws + (22l << 20));   // 2 MB   [1024][1024]
  unsigned short* qb = (unsigned short*)(ws + (24l << 20));    // 16 MB  [64][2048][64]
  unsigned short* kb = (unsigned short*)(ws + (40l << 20));    // 16 MB  [64][2048][64]
  unsigned short* vtb = (unsigned short*)(ws + (56l << 20));   // 16 MB  [64][64][2048]
  unsigned short* ob = (unsigned short*)(ws + (72l << 20));    // 16 MB  [8192][1024]

  f2b_kernel<<<2097152 / 256, 256, 0, stream>>>(x, xb, 2097152);
  f2b_kernel<<<262144 / 256, 256, 0, stream>>>((const float*)d_in[1], wqkv, 262144);
  f2b_kernel<<<262144 / 256, 256, 0, stream>>>((const float*)d_in[3], wqkv + (1l << 20), 262144);
  f2b_kernel<<<262144 / 256, 256, 0, stream>>>((const float*)d_in[5], wqkv + (2l << 20), 262144);
  f2b_kernel<<<262144 / 256, 256, 0, stream>>>((const float*)d_in[7], wob, 262144);

  qkv_gemm8<<<384, 512, 0, stream>>>(xb, wqkv, bq, bk, bv, qb, kb, vtb);
  attn_fwd<<<dim3(16, 64), 256, 0, stream>>>(qb, kb, vtb, ob);
  out_gemm<<<dim3(64, 8), 256, 0, stream>>>(ob, wob, bo, out);
}

// Round 7
// 195.264 us; speedup vs baseline: 1.1901x; 1.1901x over previous
//
#include <hip/hip_runtime.h>
#include <stdint.h>

typedef __attribute__((ext_vector_type(8))) short short8;
typedef __attribute__((ext_vector_type(4))) short short4v;
typedef __attribute__((ext_vector_type(4))) float floatx4;

#define QSCALE 0.1803368801111f /* 0.125 * log2(e): S in log2 units */

__device__ __forceinline__ unsigned short f2bf(float f) {
  unsigned int u = __float_as_uint(f);
  unsigned int r = (u + 0x7FFFu + ((u >> 16) & 1u)) >> 16;  // RNE
  return (unsigned short)r;
}

__device__ __forceinline__ unsigned int cvt_pk_bf16(float lo, float hi) {
  unsigned int r;
  asm("v_cvt_pk_bf16_f32 %0, %1, %2" : "=v"(r) : "v"(lo), "v"(hi));
  return r;
}

__device__ __forceinline__ void async_copy16(void* lds, const void* g) {
  __builtin_amdgcn_global_load_lds(
      (const __attribute__((address_space(1))) unsigned int*)g,
      (__attribute__((address_space(3))) unsigned int*)lds, 16, 0, 0);
}

// ---------------------------------------------------------------------------
// fp32 -> bf16 conversion (x)
// ---------------------------------------------------------------------------
__global__ __launch_bounds__(256) void f2b_kernel(const float* __restrict__ in,
                                                  unsigned short* __restrict__ out,
                                                  int n4) {
  int i = blockIdx.x * 256 + threadIdx.x;
  if (i >= n4) return;
  float4 v = ((const float4*)in)[i];
  short4v o;
  o[0] = (short)f2bf(v.x);
  o[1] = (short)f2bf(v.y);
  o[2] = (short)f2bf(v.z);
  o[3] = (short)f2bf(v.w);
  *(short4v*)(out + (long)i * 4) = o;
}

// all four 1024x1024 weight matrices in one launch: 1024 blocks per matrix
// (262144 float4 each), 4096 blocks total.
__global__ __launch_bounds__(256) void f2b4_kernel(
    const float* __restrict__ w0, const float* __restrict__ w1,
    const float* __restrict__ w2, const float* __restrict__ w3,
    unsigned short* __restrict__ o0, unsigned short* __restrict__ o1,
    unsigned short* __restrict__ o2, unsigned short* __restrict__ o3) {
  int which = blockIdx.x >> 10;
  const float* in = (which == 0) ? w0 : (which == 1) ? w1 : (which == 2) ? w2 : w3;
  unsigned short* out = (which == 0) ? o0 : (which == 1) ? o1 : (which == 2) ? o2 : o3;
  int i = (blockIdx.x & 1023) * 256 + threadIdx.x;
  float4 v = ((const float4*)in)[i];
  short4v o;
  o[0] = (short)f2bf(v.x);
  o[1] = (short)f2bf(v.y);
  o[2] = (short)f2bf(v.z);
  o[3] = (short)f2bf(v.w);
  *(short4v*)(out + (long)i * 4) = o;
}

// ---------------------------------------------------------------------------
// m97-structure GEMM mainloop: C[128x128] = A[128xK] * Bt[128xK]^T
// ---------------------------------------------------------------------------
__device__ __forceinline__ void gemm128_mainloop(
    const unsigned short* __restrict__ A, const unsigned short* __restrict__ Bt,
    int K, long brow, long bcol, unsigned short* As, unsigned short* Bs,
    floatx4 acc[4][4]) {
  const int tid = threadIdx.x;
  const int wave = tid >> 6;
  const int lane = tid & 63;
  const int wr = wave >> 1, wc = wave & 1;
  const int lr = lane & 15, lg = lane >> 4;

  const unsigned short* ga = A + (brow + (tid >> 2)) * (long)K + (tid & 3) * 8;
  const unsigned short* gb = Bt + (bcol + (tid >> 2)) * (long)K + (tid & 3) * 8;
  unsigned short* lA = As + wave * 512;
  unsigned short* lB = Bs + wave * 512;
  const int a_off = (wr * 64 + lr) * 32 + lg * 8;
  const int b_off = (wc * 64 + lr) * 32 + lg * 8;

  for (int kt = 0; kt < K; kt += 32) {
    __syncthreads();
    async_copy16(lA, ga);
    async_copy16(lA + 2048, ga + (long)64 * K);
    async_copy16(lB, gb);
    async_copy16(lB + 2048, gb + (long)64 * K);
    ga += 32;
    gb += 32;
    __syncthreads();
    short8 af[4], bf[4];
#pragma unroll
    for (int i = 0; i < 4; ++i) {
      af[i] = *(const short8*)(As + a_off + i * 512);
      bf[i] = *(const short8*)(Bs + b_off + i * 512);
    }
#pragma unroll
    for (int i = 0; i < 4; ++i)
#pragma unroll
      for (int j = 0; j < 4; ++j)
        acc[i][j] = __builtin_amdgcn_mfma_f32_16x16x32_bf16(af[i], bf[j], acc[i][j], 0, 0, 0);
  }
}

// ---------------------------------------------------------------------------
// QKV projection (2-phase 128²). Q pre-scaled to log2 units.
// ---------------------------------------------------------------------------
__global__ __launch_bounds__(256) void qkv_gemm(
    const unsigned short* __restrict__ xb, const unsigned short* __restrict__ wqkv,
    const float* __restrict__ bq, const float* __restrict__ bk,
    const float* __restrict__ bv, unsigned short* __restrict__ q_out,
    unsigned short* __restrict__ k_out, unsigned short* __restrict__ vt_out) {
  __shared__ unsigned short As[128 * 32];
  __shared__ unsigned short Bs[128 * 32];
  floatx4 zero = {0.f, 0.f, 0.f, 0.f};
  floatx4 acc[4][4];
#pragma unroll
  for (int i = 0; i < 4; ++i)
#pragma unroll
    for (int j = 0; j < 4; ++j) acc[i][j] = zero;

  long brow = (long)blockIdx.x * 128;
  long bcol = (long)blockIdx.y * 128;
  gemm128_mainloop(xb, wqkv, 1024, brow, bcol, As, Bs, acc);

  const int wave = threadIdx.x >> 6, lane = threadIdx.x & 63;
  const int wr = wave >> 1, wc = wave & 1, lr = lane & 15, lg = lane >> 4;
  const int kind = (int)(bcol >> 10);
  const float* bias = (kind == 0) ? bq : (kind == 1 ? bk : bv);
#pragma unroll
  for (int i = 0; i < 4; ++i)
#pragma unroll
    for (int j = 0; j < 4; ++j)
#pragma unroll
      for (int r = 0; r < 4; ++r) {
        int m = (int)brow + wr * 64 + i * 16 + lg * 4 + r;
        int n = (int)bcol + wc * 64 + j * 16 + lr;
        int f = n & 1023;
        float v = acc[i][j][r] + bias[f];
        if (kind == 0) v *= QSCALE;
        unsigned short o = f2bf(v);
        int h = f >> 6, d = f & 63;
        int b = m >> 11, t = m & 2047;
        long bh = (long)(b * 16 + h);
        if (kind == 0)
          q_out[(bh * 2048 + t) * 64 + d] = o;
        else if (kind == 1)
          k_out[(bh * 2048 + t) * 64 + d] = o;
        else
          vt_out[(bh * 64 + d) * 2048 + t] = o;
      }
}

// ---------------------------------------------------------------------------
// Output projection
// ---------------------------------------------------------------------------
__global__ __launch_bounds__(256) void out_gemm(
    const unsigned short* __restrict__ ob, const unsigned short* __restrict__ wo,
    const float* __restrict__ bo, float* __restrict__ out) {
  __shared__ unsigned short As[128 * 32];
  __shared__ unsigned short Bs[128 * 32];
  floatx4 zero = {0.f, 0.f, 0.f, 0.f};
  floatx4 acc[4][4];
#pragma unroll
  for (int i = 0; i < 4; ++i)
#pragma unroll
    for (int j = 0; j < 4; ++j) acc[i][j] = zero;

  long brow = (long)blockIdx.x * 128;
  long bcol = (long)blockIdx.y * 128;
  gemm128_mainloop(ob, wo, 1024, brow, bcol, As, Bs, acc);

  const int wave = threadIdx.x >> 6, lane = threadIdx.x & 63;
  const int wr = wave >> 1, wc = wave & 1, lr = lane & 15, lg = lane >> 4;
#pragma unroll
  for (int i = 0; i < 4; ++i)
#pragma unroll
    for (int j = 0; j < 4; ++j)
#pragma unroll
      for (int r = 0; r < 4; ++r) {
        int m = (int)brow + wr * 64 + i * 16 + lg * 4 + r;
        int n = (int)bcol + wc * 64 + j * 16 + lr;
        out[(long)m * 1024 + n] = acc[i][j][r] + bo[n];
      }
}

// ---------------------------------------------------------------------------
// Flash attention v5: 32 q-rows per wave (128/block) -> every K/V LDS frag
// feeds 2 MFMAs; 512 blocks = exactly 2/CU. LDS-staged K/V double-buffered
// (swizzled), log2-domain softmax (Q pre-scaled), defer-max, per-lane l.
// ---------------------------------------------------------------------------
__device__ __forceinline__ void stage_kv(char* __restrict__ Kb, char* __restrict__ Vb,
                                         const char* __restrict__ Kp,
                                         const char* __restrict__ Vt, int kv0,
                                         int tid) {
  const int wave = tid >> 6;
#pragma unroll
  for (int j = 0; j < 2; ++j) {
    int d = j * 256 + tid;  // chunk id 0..511
    int row = d >> 3, cc = d & 7;
    int gc = cc ^ (row & 7);
    const char* gk = Kp + (size_t)kv0 * 128 + row * 128 + gc * 16;
    async_copy16(Kb + (j * 256 + wave * 64) * 16, gk);
    const char* gv = Vt + (size_t)row * 4096 + (size_t)kv0 * 2 + gc * 16;
    async_copy16(Vb + (j * 256 + wave * 64) * 16, gv);
  }
}

__device__ __forceinline__ void attn_step(
    const char* __restrict__ Kb, const char* __restrict__ Vb,
    char* __restrict__ PTw, const short8 (&qf)[2][2],
    int kv0, int q0, int lr, int lg, bool diag,
    float (&m_i)[2], float (&l_i)[2], floatx4 (&accO)[2][4]) {
  floatx4 zero = {0.f, 0.f, 0.f, 0.f};
  const int x7 = lr & 7;
  floatx4 s[2][4];
  __builtin_amdgcn_s_setprio(1);
#pragma unroll
  for (int nt = 0; nt < 4; ++nt) {
    const char* kr = Kb + (nt * 16 + lr) * 128;
    short8 kf0 = *(const short8*)(kr + ((lg ^ x7) * 16));
    short8 kf1 = *(const short8*)(kr + (((4 + lg) ^ x7) * 16));
#pragma unroll
    for (int qa = 0; qa < 2; ++qa) {
      floatx4 a = zero;
      a = __builtin_amdgcn_mfma_f32_16x16x32_bf16(kf0, qf[qa][0], a, 0, 0, 0);
      a = __builtin_amdgcn_mfma_f32_16x16x32_bf16(kf1, qf[qa][1], a, 0, 0, 0);
      s[qa][nt] = a;
    }
  }
  __builtin_amdgcn_s_setprio(0);

  // causal mask (only near-diagonal steps); S already in log2 units
  if (diag) {
#pragma unroll
    for (int qa = 0; qa < 2; ++qa) {
      const int q = q0 + qa * 16 + lr;
#pragma unroll
      for (int nt = 0; nt < 4; ++nt)
#pragma unroll
        for (int r = 0; r < 4; ++r) {
          int kvi = kv0 + nt * 16 + lg * 4 + r;
          if (kvi > q) s[qa][nt][r] = -1e30f;
        }
    }
  }

  // in-lane row max per q-group
  float pmax[2];
#pragma unroll
  for (int qa = 0; qa < 2; ++qa) {
    float m0 = fmaxf(fmaxf(s[qa][0][0], s[qa][0][1]), fmaxf(s[qa][0][2], s[qa][0][3]));
    float m1 = fmaxf(fmaxf(s[qa][1][0], s[qa][1][1]), fmaxf(s[qa][1][2], s[qa][1][3]));
    float m2 = fmaxf(fmaxf(s[qa][2][0], s[qa][2][1]), fmaxf(s[qa][2][2], s[qa][2][3]));
    float m3 = fmaxf(fmaxf(s[qa][3][0], s[qa][3][1]), fmaxf(s[qa][3][2], s[qa][3][3]));
    pmax[qa] = fmaxf(fmaxf(m0, m1), fmaxf(m2, m3));
  }

  // defer-max: rescale only when some row's max grew by > ~8 nats (11.5 log2)
  float g = fmaxf(pmax[0] - m_i[0], pmax[1] - m_i[1]);
  if (__any(g > 11.5f)) {
#pragma unroll
    for (int qa = 0; qa < 2; ++qa) {
      float mx = fmaxf(pmax[qa], __shfl_xor(pmax[qa], 16));
      mx = fmaxf(mx, __shfl_xor(mx, 32));
      float mnew = fmaxf(m_i[qa], mx);
      float scl = exp2f(m_i[qa] - mnew);
      m_i[qa] = mnew;
      l_i[qa] *= scl;
#pragma unroll
      for (int r = 0; r < 4; ++r) {
        float so = __shfl(scl, lg * 4 + r);
#pragma unroll
        for (int dt = 0; dt < 4; ++dt) accO[qa][dt][r] *= so;
      }
    }
  }

#pragma unroll
  for (int qa = 0; qa < 2; ++qa) {
    char* prow = PTw + (qa * 16 + lr) * 128;
#pragma unroll
    for (int nt = 0; nt < 4; ++nt) {
      float p0 = exp2f(s[qa][nt][0] - m_i[qa]);
      float p1 = exp2f(s[qa][nt][1] - m_i[qa]);
      float p2 = exp2f(s[qa][nt][2] - m_i[qa]);
      float p3 = exp2f(s[qa][nt][3] - m_i[qa]);
      l_i[qa] += (p0 + p1) + (p2 + p3);
      uint2 wv;
      wv.x = cvt_pk_bf16(p0, p1);
      wv.y = cvt_pk_bf16(p2, p3);
      *(uint2*)(prow + (((2 * nt + (lg >> 1)) ^ x7) * 16) + ((2 * lg) & 3) * 4) = wv;
    }
  }

  __builtin_amdgcn_s_setprio(1);
#pragma unroll
  for (int kk = 0; kk < 2; ++kk) {
    short8 pf0 = *(const short8*)(PTw + lr * 128 + (((4 * kk + lg) ^ x7) * 16));
    short8 pf1 = *(const short8*)(PTw + (16 + lr) * 128 + (((4 * kk + lg) ^ x7) * 16));
#pragma unroll
    for (int dt = 0; dt < 4; ++dt) {
      short8 vf = *(const short8*)(Vb + (dt * 16 + lr) * 128 + (((4 * kk + lg) ^ x7) * 16));
      accO[0][dt] = __builtin_amdgcn_mfma_f32_16x16x32_bf16(pf0, vf, accO[0][dt], 0, 0, 0);
      accO[1][dt] = __builtin_amdgcn_mfma_f32_16x16x32_bf16(pf1, vf, accO[1][dt], 0, 0, 0);
    }
  }
  __builtin_amdgcn_s_setprio(0);
}

__global__ __launch_bounds__(256, 2) void attn_fwd(
    const unsigned short* __restrict__ qb, const unsigned short* __restrict__ kb,
    const unsigned short* __restrict__ vtb, unsigned short* __restrict__ ob) {
  __shared__ __align__(16) char Kbuf[2][8192];
  __shared__ __align__(16) char Vbuf[2][8192];
  __shared__ __align__(16) char PTbuf[4][4096];

  // xcd = linear_wg%8 = blockIdx.x (gridDim.x==8): all 8 q-blocks of a head
  // share an XCD; 8 heads per XCD = 4 MB K/V working set = L2-resident.
  const int bh = blockIdx.x * 8 + (blockIdx.y & 7);
  const int pr = blockIdx.y >> 3;  // 0..7

  const int tid = threadIdx.x;
  const int wave = tid >> 6, lane = tid & 63;
  const int lr = lane & 15, lg = lane >> 4;
  const unsigned short* Q = qb + (long)bh * 2048 * 64;
  const char* Kp = (const char*)(kb + (long)bh * 2048 * 64);
  const char* Vt = (const char*)(vtb + (long)bh * 64 * 2048);
  const int b = bh >> 4, h = bh & 15;
  char* PTw = PTbuf[wave];

  floatx4 zero = {0.f, 0.f, 0.f, 0.f};

#pragma unroll 1
  for (int half = 0; half < 2; ++half) {
    const int qt = half ? (15 - pr) : pr;       // 128-row q-tile index
    const int q0 = qt * 128 + wave * 32;
    const int nkv = 2 * qt + 2;

    short8 qf[2][2];
#pragma unroll
    for (int qa = 0; qa < 2; ++qa)
#pragma unroll
      for (int kk = 0; kk < 2; ++kk)
        qf[qa][kk] = *(const short8*)(Q + (q0 + qa * 16 + lr) * 64 + kk * 32 + lg * 8);

    floatx4 accO[2][4];
#pragma unroll
    for (int qa = 0; qa < 2; ++qa)
#pragma unroll
      for (int dt = 0; dt < 4; ++dt) accO[qa][dt] = zero;
    float m_i[2] = {-1e30f, -1e30f};
    float l_i[2] = {0.f, 0.f};

    stage_kv(Kbuf[0], Vbuf[0], Kp, Vt, 0, tid);
    __syncthreads();
#pragma unroll 1
    for (int kv = 0; kv < nkv; ++kv) {
      if (kv + 1 < nkv)
        stage_kv(Kbuf[(kv + 1) & 1], Vbuf[(kv + 1) & 1], Kp, Vt, (kv + 1) * 64, tid);
      attn_step(Kbuf[kv & 1], Vbuf[kv & 1], PTw, qf, kv * 64, q0, lr, lg,
                kv >= 2 * qt, m_i, l_i, accO);
      __syncthreads();
    }

#pragma unroll
    for (int qa = 0; qa < 2; ++qa) {
      float lt = l_i[qa] + __shfl_xor(l_i[qa], 16);
      lt += __shfl_xor(lt, 32);
      float linv = 1.f / lt;
#pragma unroll
      for (int r = 0; r < 4; ++r) {
        float io = __shfl(linv, lg * 4 + r);
        int tq = q0 + qa * 16 + 4 * lg + r;
#pragma unroll
        for (int dt = 0; dt < 4; ++dt)
          ob[((long)b * 2048 + tq) * 1024 + h * 64 + dt * 16 + lr] =
              f2bf(accO[qa][dt][r] * io);
      }
    }
  }
}

// ---------------------------------------------------------------------------
extern "C" void kernel_launch(void* const* d_in, const int* in_sizes, int n_in,
                              void* d_out, int out_size, void* d_ws, size_t ws_size,
                              hipStream_t stream) {
  const float* x = (const float*)d_in[0];
  const float* bq = (const float*)d_in[2];
  const float* bk = (const float*)d_in[4];
  const float* bv = (const float*)d_in[6];
  const float* bo = (const float*)d_in[8];
  float* out = (float*)d_out;

  char* ws = (char*)d_ws;
  unsigned short* xb = (unsigned short*)(ws);                  // 16 MB  [8192][1024]
  unsigned short* wqkv = (unsigned short*)(ws + (16l << 20));  // 6 MB   [3072][1024]
  unsigned short* wob = (unsigned short*)(ws + (22l << 20));   // 2 MB   [1024][1024]
  unsigned short* qb = (unsigned short*)(ws + (24l << 20));    // 16 MB  [64][2048][64]
  unsigned short* kb = (unsigned short*)(ws + (40l << 20));    // 16 MB  [64][2048][64]
  unsigned short* vtb = (unsigned short*)(ws + (56l << 20));   // 16 MB  [64][64][2048]
  unsigned short* ob = (unsigned short*)(ws + (72l << 20));    // 16 MB  [8192][1024]

  f2b_kernel<<<2097152 / 256, 256, 0, stream>>>(x, xb, 2097152);
  f2b4_kernel<<<4096, 256, 0, stream>>>(
      (const float*)d_in[1], (const float*)d_in[3], (const float*)d_in[5],
      (const float*)d_in[7], wqkv, wqkv + (1l << 20), wqkv + (2l << 20), wob);

  qkv_gemm<<<dim3(64, 24), 256, 0, stream>>>(xb, wqkv, bq, bk, bv, qb, kb, vtb);
  attn_fwd<<<dim3(8, 64), 256, 0, stream>>>(qb, kb, vtb, ob);
  out_gemm<<<dim3(64, 8), 256, 0, stream>>>(ob, wob, bo, out);
}

// Round 8
// 192.011 us; speedup vs baseline: 1.2102x; 1.0169x over previous
//
#include <hip/hip_runtime.h>
#include <stdint.h>

typedef __attribute__((ext_vector_type(8))) short short8;
typedef __attribute__((ext_vector_type(4))) short short4v;
typedef __attribute__((ext_vector_type(4))) float floatx4;

#define QSCALE 0.1803368801111f /* 0.125 * log2(e): S in log2 units */

__device__ __forceinline__ unsigned short f2bf(float f) {
  unsigned int u = __float_as_uint(f);
  unsigned int r = (u + 0x7FFFu + ((u >> 16) & 1u)) >> 16;  // RNE
  return (unsigned short)r;
}

__device__ __forceinline__ unsigned int cvt_pk_bf16(float lo, float hi) {
  unsigned int r;
  asm("v_cvt_pk_bf16_f32 %0, %1, %2" : "=v"(r) : "v"(lo), "v"(hi));
  return r;
}

__device__ __forceinline__ void async_copy16(void* lds, const void* g) {
  __builtin_amdgcn_global_load_lds(
      (const __attribute__((address_space(1))) unsigned int*)g,
      (__attribute__((address_space(3))) unsigned int*)lds, 16, 0, 0);
}

// ---------------------------------------------------------------------------
// ALL fp32 -> bf16 conversions in one launch:
//   blocks [0,8192)        : x  (2,097,152 float4)
//   blocks [8192,8192+4096): w0..w3, 1024 blocks each (262,144 float4)
// ---------------------------------------------------------------------------
__global__ __launch_bounds__(256) void f2ball_kernel(
    const float* __restrict__ x, unsigned short* __restrict__ xb,
    const float* __restrict__ w0, const float* __restrict__ w1,
    const float* __restrict__ w2, const float* __restrict__ w3,
    unsigned short* __restrict__ o0, unsigned short* __restrict__ o1,
    unsigned short* __restrict__ o2, unsigned short* __restrict__ o3) {
  const float* in;
  unsigned short* out;
  long i;
  if (blockIdx.x < 8192) {
    in = x;
    out = xb;
    i = (long)blockIdx.x * 256 + threadIdx.x;
  } else {
    int wb = blockIdx.x - 8192;
    int which = wb >> 10;
    in = (which == 0) ? w0 : (which == 1) ? w1 : (which == 2) ? w2 : w3;
    out = (which == 0) ? o0 : (which == 1) ? o1 : (which == 2) ? o2 : o3;
    i = (long)(wb & 1023) * 256 + threadIdx.x;
  }
  float4 v = ((const float4*)in)[i];
  short4v o;
  o[0] = (short)f2bf(v.x);
  o[1] = (short)f2bf(v.y);
  o[2] = (short)f2bf(v.z);
  o[3] = (short)f2bf(v.w);
  *(short4v*)(out + i * 4) = o;
}

// ---------------------------------------------------------------------------
// Double-buffered 2-phase GEMM mainloop: C[128x128] = A[128xK] * Bt[128xK]^T.
// Stage tile t+1 into buf^1 BEFORE computing tile t; ONE __syncthreads per
// K-step (catalog T3-minimum; m248v2: 1.10x vs 2-barrier m97 structure).
// As/Bs are [2][128][32] bf16 (16 KB each buffer half, 32 KB total).
// ---------------------------------------------------------------------------
__device__ __forceinline__ void gemm128_mainloop_db(
    const unsigned short* __restrict__ A, const unsigned short* __restrict__ Bt,
    int K, long brow, long bcol, unsigned short* As, unsigned short* Bs,
    floatx4 acc[4][4]) {
  const int tid = threadIdx.x;
  const int wave = tid >> 6;
  const int lane = tid & 63;
  const int wr = wave >> 1, wc = wave & 1;
  const int lr = lane & 15, lg = lane >> 4;

  const unsigned short* ga = A + (brow + (tid >> 2)) * (long)K + (tid & 3) * 8;
  const unsigned short* gb = Bt + (bcol + (tid >> 2)) * (long)K + (tid & 3) * 8;
  const int woff = wave * 512;
  const int a_off = (wr * 64 + lr) * 32 + lg * 8;
  const int b_off = (wc * 64 + lr) * 32 + lg * 8;

  // prologue: stage tile 0 -> buf 0
  async_copy16(As + woff, ga);
  async_copy16(As + woff + 2048, ga + (long)64 * K);
  async_copy16(Bs + woff, gb);
  async_copy16(Bs + woff + 2048, gb + (long)64 * K);
  ga += 32;
  gb += 32;
  __syncthreads();

  int buf = 0;
  for (int kt = 0; kt < K; kt += 32) {
    // stage next tile into the other buffer (flies under the MFMA below)
    if (kt + 32 < K) {
      unsigned short* lA = As + (buf ^ 1) * 4096 + woff;
      unsigned short* lB = Bs + (buf ^ 1) * 4096 + woff;
      async_copy16(lA, ga);
      async_copy16(lA + 2048, ga + (long)64 * K);
      async_copy16(lB, gb);
      async_copy16(lB + 2048, gb + (long)64 * K);
      ga += 32;
      gb += 32;
    }
    const unsigned short* Ab = As + buf * 4096;
    const unsigned short* Bb = Bs + buf * 4096;
    short8 af[4], bf[4];
#pragma unroll
    for (int i = 0; i < 4; ++i) {
      af[i] = *(const short8*)(Ab + a_off + i * 512);
      bf[i] = *(const short8*)(Bb + b_off + i * 512);
    }
#pragma unroll
    for (int i = 0; i < 4; ++i)
#pragma unroll
      for (int j = 0; j < 4; ++j)
        acc[i][j] = __builtin_amdgcn_mfma_f32_16x16x32_bf16(af[i], bf[j], acc[i][j], 0, 0, 0);
    __syncthreads();  // drains stage writes (vmcnt) + all waves done reading
    buf ^= 1;
  }
}

// ---------------------------------------------------------------------------
// QKV projection. Q pre-scaled to log2 units.
// ---------------------------------------------------------------------------
__global__ __launch_bounds__(256, 4) void qkv_gemm(
    const unsigned short* __restrict__ xb, const unsigned short* __restrict__ wqkv,
    const float* __restrict__ bq, const float* __restrict__ bk,
    const float* __restrict__ bv, unsigned short* __restrict__ q_out,
    unsigned short* __restrict__ k_out, unsigned short* __restrict__ vt_out) {
  __shared__ unsigned short As[2 * 128 * 32];
  __shared__ unsigned short Bs[2 * 128 * 32];
  floatx4 zero = {0.f, 0.f, 0.f, 0.f};
  floatx4 acc[4][4];
#pragma unroll
  for (int i = 0; i < 4; ++i)
#pragma unroll
    for (int j = 0; j < 4; ++j) acc[i][j] = zero;

  long brow = (long)blockIdx.x * 128;
  long bcol = (long)blockIdx.y * 128;
  gemm128_mainloop_db(xb, wqkv, 1024, brow, bcol, As, Bs, acc);

  const int wave = threadIdx.x >> 6, lane = threadIdx.x & 63;
  const int wr = wave >> 1, wc = wave & 1, lr = lane & 15, lg = lane >> 4;
  const int kind = (int)(bcol >> 10);
  const float* bias = (kind == 0) ? bq : (kind == 1 ? bk : bv);
#pragma unroll
  for (int i = 0; i < 4; ++i)
#pragma unroll
    for (int j = 0; j < 4; ++j)
#pragma unroll
      for (int r = 0; r < 4; ++r) {
        int m = (int)brow + wr * 64 + i * 16 + lg * 4 + r;
        int n = (int)bcol + wc * 64 + j * 16 + lr;
        int f = n & 1023;
        float v = acc[i][j][r] + bias[f];
        if (kind == 0) v *= QSCALE;
        unsigned short o = f2bf(v);
        int h = f >> 6, d = f & 63;
        int b = m >> 11, t = m & 2047;
        long bh = (long)(b * 16 + h);
        if (kind == 0)
          q_out[(bh * 2048 + t) * 64 + d] = o;
        else if (kind == 1)
          k_out[(bh * 2048 + t) * 64 + d] = o;
        else
          vt_out[(bh * 64 + d) * 2048 + t] = o;
      }
}

// ---------------------------------------------------------------------------
// Output projection
// ---------------------------------------------------------------------------
__global__ __launch_bounds__(256, 4) void out_gemm(
    const unsigned short* __restrict__ ob, const unsigned short* __restrict__ wo,
    const float* __restrict__ bo, float* __restrict__ out) {
  __shared__ unsigned short As[2 * 128 * 32];
  __shared__ unsigned short Bs[2 * 128 * 32];
  floatx4 zero = {0.f, 0.f, 0.f, 0.f};
  floatx4 acc[4][4];
#pragma unroll
  for (int i = 0; i < 4; ++i)
#pragma unroll
    for (int j = 0; j < 4; ++j) acc[i][j] = zero;

  long brow = (long)blockIdx.x * 128;
  long bcol = (long)blockIdx.y * 128;
  gemm128_mainloop_db(ob, wo, 1024, brow, bcol, As, Bs, acc);

  const int wave = threadIdx.x >> 6, lane = threadIdx.x & 63;
  const int wr = wave >> 1, wc = wave & 1, lr = lane & 15, lg = lane >> 4;
#pragma unroll
  for (int i = 0; i < 4; ++i)
#pragma unroll
    for (int j = 0; j < 4; ++j)
#pragma unroll
      for (int r = 0; r < 4; ++r) {
        int m = (int)brow + wr * 64 + i * 16 + lg * 4 + r;
        int n = (int)bcol + wc * 64 + j * 16 + lr;
        out[(long)m * 1024 + n] = acc[i][j][r] + bo[n];
      }
}

// ---------------------------------------------------------------------------
// Flash attention v5 (unchanged, passing): 32 q-rows per wave, LDS-staged K/V
// double-buffered (swizzled), log2-domain softmax, defer-max, per-lane l.
// ---------------------------------------------------------------------------
__device__ __forceinline__ void stage_kv(char* __restrict__ Kb, char* __restrict__ Vb,
                                         const char* __restrict__ Kp,
                                         const char* __restrict__ Vt, int kv0,
                                         int tid) {
  const int wave = tid >> 6;
#pragma unroll
  for (int j = 0; j < 2; ++j) {
    int d = j * 256 + tid;  // chunk id 0..511
    int row = d >> 3, cc = d & 7;
    int gc = cc ^ (row & 7);
    const char* gk = Kp + (size_t)kv0 * 128 + row * 128 + gc * 16;
    async_copy16(Kb + (j * 256 + wave * 64) * 16, gk);
    const char* gv = Vt + (size_t)row * 4096 + (size_t)kv0 * 2 + gc * 16;
    async_copy16(Vb + (j * 256 + wave * 64) * 16, gv);
  }
}

__device__ __forceinline__ void attn_step(
    const char* __restrict__ Kb, const char* __restrict__ Vb,
    char* __restrict__ PTw, const short8 (&qf)[2][2],
    int kv0, int q0, int lr, int lg, bool diag,
    float (&m_i)[2], float (&l_i)[2], floatx4 (&accO)[2][4]) {
  floatx4 zero = {0.f, 0.f, 0.f, 0.f};
  const int x7 = lr & 7;
  floatx4 s[2][4];
  __builtin_amdgcn_s_setprio(1);
#pragma unroll
  for (int nt = 0; nt < 4; ++nt) {
    const char* kr = Kb + (nt * 16 + lr) * 128;
    short8 kf0 = *(const short8*)(kr + ((lg ^ x7) * 16));
    short8 kf1 = *(const short8*)(kr + (((4 + lg) ^ x7) * 16));
#pragma unroll
    for (int qa = 0; qa < 2; ++qa) {
      floatx4 a = zero;
      a = __builtin_amdgcn_mfma_f32_16x16x32_bf16(kf0, qf[qa][0], a, 0, 0, 0);
      a = __builtin_amdgcn_mfma_f32_16x16x32_bf16(kf1, qf[qa][1], a, 0, 0, 0);
      s[qa][nt] = a;
    }
  }
  __builtin_amdgcn_s_setprio(0);

  if (diag) {
#pragma unroll
    for (int qa = 0; qa < 2; ++qa) {
      const int q = q0 + qa * 16 + lr;
#pragma unroll
      for (int nt = 0; nt < 4; ++nt)
#pragma unroll
        for (int r = 0; r < 4; ++r) {
          int kvi = kv0 + nt * 16 + lg * 4 + r;
          if (kvi > q) s[qa][nt][r] = -1e30f;
        }
    }
  }

  float pmax[2];
#pragma unroll
  for (int qa = 0; qa < 2; ++qa) {
    float m0 = fmaxf(fmaxf(s[qa][0][0], s[qa][0][1]), fmaxf(s[qa][0][2], s[qa][0][3]));
    float m1 = fmaxf(fmaxf(s[qa][1][0], s[qa][1][1]), fmaxf(s[qa][1][2], s[qa][1][3]));
    float m2 = fmaxf(fmaxf(s[qa][2][0], s[qa][2][1]), fmaxf(s[qa][2][2], s[qa][2][3]));
    float m3 = fmaxf(fmaxf(s[qa][3][0], s[qa][3][1]), fmaxf(s[qa][3][2], s[qa][3][3]));
    pmax[qa] = fmaxf(fmaxf(m0, m1), fmaxf(m2, m3));
  }

  float g = fmaxf(pmax[0] - m_i[0], pmax[1] - m_i[1]);
  if (__any(g > 11.5f)) {
#pragma unroll
    for (int qa = 0; qa < 2; ++qa) {
      float mx = fmaxf(pmax[qa], __shfl_xor(pmax[qa], 16));
      mx = fmaxf(mx, __shfl_xor(mx, 32));
      float mnew = fmaxf(m_i[qa], mx);
      float scl = exp2f(m_i[qa] - mnew);
      m_i[qa] = mnew;
      l_i[qa] *= scl;
#pragma unroll
      for (int r = 0; r < 4; ++r) {
        float so = __shfl(scl, lg * 4 + r);
#pragma unroll
        for (int dt = 0; dt < 4; ++dt) accO[qa][dt][r] *= so;
      }
    }
  }

#pragma unroll
  for (int qa = 0; qa < 2; ++qa) {
    char* prow = PTw + (qa * 16 + lr) * 128;
#pragma unroll
    for (int nt = 0; nt < 4; ++nt) {
      float p0 = exp2f(s[qa][nt][0] - m_i[qa]);
      float p1 = exp2f(s[qa][nt][1] - m_i[qa]);
      float p2 = exp2f(s[qa][nt][2] - m_i[qa]);
      float p3 = exp2f(s[qa][nt][3] - m_i[qa]);
      l_i[qa] += (p0 + p1) + (p2 + p3);
      uint2 wv;
      wv.x = cvt_pk_bf16(p0, p1);
      wv.y = cvt_pk_bf16(p2, p3);
      *(uint2*)(prow + (((2 * nt + (lg >> 1)) ^ x7) * 16) + ((2 * lg) & 3) * 4) = wv;
    }
  }

  __builtin_amdgcn_s_setprio(1);
#pragma unroll
  for (int kk = 0; kk < 2; ++kk) {
    short8 pf0 = *(const short8*)(PTw + lr * 128 + (((4 * kk + lg) ^ x7) * 16));
    short8 pf1 = *(const short8*)(PTw + (16 + lr) * 128 + (((4 * kk + lg) ^ x7) * 16));
#pragma unroll
    for (int dt = 0; dt < 4; ++dt) {
      short8 vf = *(const short8*)(Vb + (dt * 16 + lr) * 128 + (((4 * kk + lg) ^ x7) * 16));
      accO[0][dt] = __builtin_amdgcn_mfma_f32_16x16x32_bf16(pf0, vf, accO[0][dt], 0, 0, 0);
      accO[1][dt] = __builtin_amdgcn_mfma_f32_16x16x32_bf16(pf1, vf, accO[1][dt], 0, 0, 0);
    }
  }
  __builtin_amdgcn_s_setprio(0);
}

__global__ __launch_bounds__(256, 2) void attn_fwd(
    const unsigned short* __restrict__ qb, const unsigned short* __restrict__ kb,
    const unsigned short* __restrict__ vtb, unsigned short* __restrict__ ob) {
  __shared__ __align__(16) char Kbuf[2][8192];
  __shared__ __align__(16) char Vbuf[2][8192];
  __shared__ __align__(16) char PTbuf[4][4096];

  const int bh = blockIdx.x * 8 + (blockIdx.y & 7);
  const int pr = blockIdx.y >> 3;  // 0..7

  const int tid = threadIdx.x;
  const int wave = tid >> 6, lane = tid & 63;
  const int lr = lane & 15, lg = lane >> 4;
  const unsigned short* Q = qb + (long)bh * 2048 * 64;
  const char* Kp = (const char*)(kb + (long)bh * 2048 * 64);
  const char* Vt = (const char*)(vtb + (long)bh * 64 * 2048);
  const int b = bh >> 4, h = bh & 15;
  char* PTw = PTbuf[wave];

  floatx4 zero = {0.f, 0.f, 0.f, 0.f};

#pragma unroll 1
  for (int half = 0; half < 2; ++half) {
    const int qt = half ? (15 - pr) : pr;  // 128-row q-tile index
    const int q0 = qt * 128 + wave * 32;
    const int nkv = 2 * qt + 2;

    short8 qf[2][2];
#pragma unroll
    for (int qa = 0; qa < 2; ++qa)
#pragma unroll
      for (int kk = 0; kk < 2; ++kk)
        qf[qa][kk] = *(const short8*)(Q + (q0 + qa * 16 + lr) * 64 + kk * 32 + lg * 8);

    floatx4 accO[2][4];
#pragma unroll
    for (int qa = 0; qa < 2; ++qa)
#pragma unroll
      for (int dt = 0; dt < 4; ++dt) accO[qa][dt] = zero;
    float m_i[2] = {-1e30f, -1e30f};
    float l_i[2] = {0.f, 0.f};

    stage_kv(Kbuf[0], Vbuf[0], Kp, Vt, 0, tid);
    __syncthreads();
#pragma unroll 1
    for (int kv = 0; kv < nkv; ++kv) {
      if (kv + 1 < nkv)
        stage_kv(Kbuf[(kv + 1) & 1], Vbuf[(kv + 1) & 1], Kp, Vt, (kv + 1) * 64, tid);
      attn_step(Kbuf[kv & 1], Vbuf[kv & 1], PTw, qf, kv * 64, q0, lr, lg,
                kv >= 2 * qt, m_i, l_i, accO);
      __syncthreads();
    }

#pragma unroll
    for (int qa = 0; qa < 2; ++qa) {
      float lt = l_i[qa] + __shfl_xor(l_i[qa], 16);
      lt += __shfl_xor(lt, 32);
      float linv = 1.f / lt;
#pragma unroll
      for (int r = 0; r < 4; ++r) {
        float io = __shfl(linv, lg * 4 + r);
        int tq = q0 + qa * 16 + 4 * lg + r;
#pragma unroll
        for (int dt = 0; dt < 4; ++dt)
          ob[((long)b * 2048 + tq) * 1024 + h * 64 + dt * 16 + lr] =
              f2bf(accO[qa][dt][r] * io);
      }
    }
  }
}

// ---------------------------------------------------------------------------
extern "C" void kernel_launch(void* const* d_in, const int* in_sizes, int n_in,
                              void* d_out, int out_size, void* d_ws, size_t ws_size,
                              hipStream_t stream) {
  const float* x = (const float*)d_in[0];
  const float* bq = (const float*)d_in[2];
  const float* bk = (const float*)d_in[4];
  const float* bv = (const float*)d_in[6];
  const float* bo = (const float*)d_in[8];
  float* out = (float*)d_out;

  char* ws = (char*)d_ws;
  unsigned short* xb = (unsigned short*)(ws);                  // 16 MB  [8192][1024]
  unsigned short* wqkv = (unsigned short*)(ws + (16l << 20));  // 6 MB   [3072][1024]
  unsigned short* wob = (unsigned short*)(ws + (22l << 20));   // 2 MB   [1024][1024]
  unsigned short* qb = (unsigned short*)(ws + (24l << 20));    // 16 MB  [64][2048][64]
  unsigned short* kb = (unsigned short*)(ws + (40l << 20));    // 16 MB  [64][2048][64]
  unsigned short* vtb = (unsigned short*)(ws + (56l << 20));   // 16 MB  [64][64][2048]
  unsigned short* ob = (unsigned short*)(ws + (72l << 20));    // 16 MB  [8192][1024]

  f2ball_kernel<<<12288, 256, 0, stream>>>(
      x, xb, (const float*)d_in[1], (const float*)d_in[3], (const float*)d_in[5],
      (const float*)d_in[7], wqkv, wqkv + (1l << 20), wqkv + (2l << 20), wob);

  qkv_gemm<<<dim3(64, 24), 256, 0, stream>>>(xb, wqkv, bq, bk, bv, qb, kb, vtb);
  attn_fwd<<<dim3(8, 64), 256, 0, stream>>>(qb, kb, vtb, ob);
  out_gemm<<<dim3(64, 8), 256, 0, stream>>>(ob, wob, bo, out);
}

// Round 9
// 171.879 us; speedup vs baseline: 1.3520x; 1.1171x over previous
//
#include <hip/hip_runtime.h>
#include <stdint.h>

typedef __attribute__((ext_vector_type(8))) short short8;
typedef __attribute__((ext_vector_type(4))) short short4v;
typedef __attribute__((ext_vector_type(4))) float floatx4;

#define QSCALE 0.1803368801111f /* 0.125 * log2(e): S in log2 units */

__device__ __forceinline__ unsigned short f2bf(float f) {
  unsigned int u = __float_as_uint(f);
  unsigned int r = (u + 0x7FFFu + ((u >> 16) & 1u)) >> 16;  // RNE
  return (unsigned short)r;
}

__device__ __forceinline__ unsigned int cvt_pk_bf16(float lo, float hi) {
  unsigned int r;
  asm("v_cvt_pk_bf16_f32 %0, %1, %2" : "=v"(r) : "v"(lo), "v"(hi));
  return r;
}

__device__ __forceinline__ void async_copy16(void* lds, const void* g) {
  __builtin_amdgcn_global_load_lds(
      (const __attribute__((address_space(1))) unsigned int*)g,
      (__attribute__((address_space(3))) unsigned int*)lds, 16, 0, 0);
}

// ---------------------------------------------------------------------------
// ALL fp32 -> bf16 conversions in one launch.
// ---------------------------------------------------------------------------
__global__ __launch_bounds__(256) void f2ball_kernel(
    const float* __restrict__ x, unsigned short* __restrict__ xb,
    const float* __restrict__ w0, const float* __restrict__ w1,
    const float* __restrict__ w2, const float* __restrict__ w3,
    unsigned short* __restrict__ o0, unsigned short* __restrict__ o1,
    unsigned short* __restrict__ o2, unsigned short* __restrict__ o3) {
  const float* in;
  unsigned short* out;
  long i;
  if (blockIdx.x < 8192) {
    in = x;
    out = xb;
    i = (long)blockIdx.x * 256 + threadIdx.x;
  } else {
    int wb = blockIdx.x - 8192;
    int which = wb >> 10;
    in = (which == 0) ? w0 : (which == 1) ? w1 : (which == 2) ? w2 : w3;
    out = (which == 0) ? o0 : (which == 1) ? o1 : (which == 2) ? o2 : o3;
    i = (long)(wb & 1023) * 256 + threadIdx.x;
  }
  float4 v = ((const float4*)in)[i];
  short4v o;
  o[0] = (short)f2bf(v.x);
  o[1] = (short)f2bf(v.y);
  o[2] = (short)f2bf(v.z);
  o[3] = (short)f2bf(v.w);
  *(short4v*)(out + i * 4) = o;
}

// ---------------------------------------------------------------------------
// Double-buffered 2-phase GEMM mainloop (1 barrier per K-step).
// ---------------------------------------------------------------------------
__device__ __forceinline__ void gemm128_mainloop_db(
    const unsigned short* __restrict__ A, const unsigned short* __restrict__ Bt,
    int K, long brow, long bcol, unsigned short* As, unsigned short* Bs,
    floatx4 acc[4][4]) {
  const int tid = threadIdx.x;
  const int wave = tid >> 6;
  const int lane = tid & 63;
  const int wr = wave >> 1, wc = wave & 1;
  const int lr = lane & 15, lg = lane >> 4;

  const unsigned short* ga = A + (brow + (tid >> 2)) * (long)K + (tid & 3) * 8;
  const unsigned short* gb = Bt + (bcol + (tid >> 2)) * (long)K + (tid & 3) * 8;
  const int woff = wave * 512;
  const int a_off = (wr * 64 + lr) * 32 + lg * 8;
  const int b_off = (wc * 64 + lr) * 32 + lg * 8;

  async_copy16(As + woff, ga);
  async_copy16(As + woff + 2048, ga + (long)64 * K);
  async_copy16(Bs + woff, gb);
  async_copy16(Bs + woff + 2048, gb + (long)64 * K);
  ga += 32;
  gb += 32;
  __syncthreads();

  int buf = 0;
  for (int kt = 0; kt < K; kt += 32) {
    if (kt + 32 < K) {
      unsigned short* lA = As + (buf ^ 1) * 4096 + woff;
      unsigned short* lB = Bs + (buf ^ 1) * 4096 + woff;
      async_copy16(lA, ga);
      async_copy16(lA + 2048, ga + (long)64 * K);
      async_copy16(lB, gb);
      async_copy16(lB + 2048, gb + (long)64 * K);
      ga += 32;
      gb += 32;
    }
    const unsigned short* Ab = As + buf * 4096;
    const unsigned short* Bb = Bs + buf * 4096;
    short8 af[4], bf[4];
#pragma unroll
    for (int i = 0; i < 4; ++i) {
      af[i] = *(const short8*)(Ab + a_off + i * 512);
      bf[i] = *(const short8*)(Bb + b_off + i * 512);
    }
#pragma unroll
    for (int i = 0; i < 4; ++i)
#pragma unroll
      for (int j = 0; j < 4; ++j)
        acc[i][j] = __builtin_amdgcn_mfma_f32_16x16x32_bf16(af[i], bf[j], acc[i][j], 0, 0, 0);
    __syncthreads();
    buf ^= 1;
  }
}

// ---------------------------------------------------------------------------
// QKV projection. Q pre-scaled to log2 units. V-epilogue transposes the
// 128x128 tile through LDS so vt stores are 16B-contiguous in t.
// ---------------------------------------------------------------------------
__global__ __launch_bounds__(256, 4) void qkv_gemm(
    const unsigned short* __restrict__ xb, const unsigned short* __restrict__ wqkv,
    const float* __restrict__ bq, const float* __restrict__ bk,
    const float* __restrict__ bv, unsigned short* __restrict__ q_out,
    unsigned short* __restrict__ k_out, unsigned short* __restrict__ vt_out) {
  __shared__ __align__(16) unsigned short Sh[128 * 136];  // 34 KB: GEMM dbuf + V transpose
  unsigned short* As = Sh;
  unsigned short* Bs = Sh + 8192;
  floatx4 zero = {0.f, 0.f, 0.f, 0.f};
  floatx4 acc[4][4];
#pragma unroll
  for (int i = 0; i < 4; ++i)
#pragma unroll
    for (int j = 0; j < 4; ++j) acc[i][j] = zero;

  long brow = (long)blockIdx.x * 128;
  long bcol = (long)blockIdx.y * 128;
  gemm128_mainloop_db(xb, wqkv, 1024, brow, bcol, As, Bs, acc);

  const int wave = threadIdx.x >> 6, lane = threadIdx.x & 63;
  const int wr = wave >> 1, wc = wave & 1, lr = lane & 15, lg = lane >> 4;
  const int kind = (int)(bcol >> 10);
  const float* bias = (kind == 0) ? bq : (kind == 1 ? bk : bv);

  if (kind == 2) {
    // stage tile to LDS as [n(d)][m(t)], stride 136 (2-way banks, free)
#pragma unroll
    for (int i = 0; i < 4; ++i)
#pragma unroll
      for (int j = 0; j < 4; ++j) {
        int n_local = wc * 64 + j * 16 + lr;
        int m_base = wr * 64 + i * 16 + lg * 4;
        float bsc = bias[(int)((bcol + n_local) & 1023)];
        short4v pk;
#pragma unroll
        for (int r = 0; r < 4; ++r) pk[r] = (short)f2bf(acc[i][j][r] + bsc);
        *(short4v*)(Sh + n_local * 136 + m_base) = pk;
      }
    __syncthreads();
    const int b = (int)(brow >> 11);
    const int t0 = (int)(brow & 2047);
    const int f0 = (int)(bcol - 2048);
#pragma unroll
    for (int p = 0; p < 8; ++p) {
      int c = p * 256 + threadIdx.x;
      int d_loc = c >> 4, tc = c & 15;
      short8 v = *(const short8*)(Sh + d_loc * 136 + tc * 8);
      int h = (f0 >> 6) + (d_loc >> 6);
      int d = d_loc & 63;
      *(short8*)(vt_out + ((long)((b * 16 + h) * 64 + d)) * 2048 + t0 + tc * 8) = v;
    }
  } else {
#pragma unroll
    for (int i = 0; i < 4; ++i)
#pragma unroll
      for (int j = 0; j < 4; ++j)
#pragma unroll
        for (int r = 0; r < 4; ++r) {
          int m = (int)brow + wr * 64 + i * 16 + lg * 4 + r;
          int n = (int)bcol + wc * 64 + j * 16 + lr;
          int f = n & 1023;
          float v = acc[i][j][r] + bias[f];
          if (kind == 0) v *= QSCALE;
          unsigned short o = f2bf(v);
          int h = f >> 6, d = f & 63;
          int bb = m >> 11, t = m & 2047;
          long bh = (long)(bb * 16 + h);
          if (kind == 0)
            q_out[(bh * 2048 + t) * 64 + d] = o;
          else
            k_out[(bh * 2048 + t) * 64 + d] = o;
        }
  }
}

// ---------------------------------------------------------------------------
// Output projection
// ---------------------------------------------------------------------------
__global__ __launch_bounds__(256, 4) void out_gemm(
    const unsigned short* __restrict__ ob, const unsigned short* __restrict__ wo,
    const float* __restrict__ bo, float* __restrict__ out) {
  __shared__ unsigned short As[2 * 128 * 32];
  __shared__ unsigned short Bs[2 * 128 * 32];
  floatx4 zero = {0.f, 0.f, 0.f, 0.f};
  floatx4 acc[4][4];
#pragma unroll
  for (int i = 0; i < 4; ++i)
#pragma unroll
    for (int j = 0; j < 4; ++j) acc[i][j] = zero;

  long brow = (long)blockIdx.x * 128;
  long bcol = (long)blockIdx.y * 128;
  gemm128_mainloop_db(ob, wo, 1024, brow, bcol, As, Bs, acc);

  const int wave = threadIdx.x >> 6, lane = threadIdx.x & 63;
  const int wr = wave >> 1, wc = wave & 1, lr = lane & 15, lg = lane >> 4;
#pragma unroll
  for (int i = 0; i < 4; ++i)
#pragma unroll
    for (int j = 0; j < 4; ++j)
#pragma unroll
      for (int r = 0; r < 4; ++r) {
        int m = (int)brow + wr * 64 + i * 16 + lg * 4 + r;
        int n = (int)bcol + wc * 64 + j * 16 + lr;
        out[(long)m * 1024 + n] = acc[i][j][r] + bo[n];
      }
}

// ---------------------------------------------------------------------------
// Flash attention v6: tri-buffered K/V, QK^T of tile kv+1 issued BEFORE
// softmax(kv)+PV(kv) (single-wave MFMA/VALU overlap — T15 mechanism).
// 32 q-rows/wave, log2-domain softmax, defer-max, per-lane l.
// ---------------------------------------------------------------------------
__device__ __forceinline__ void stage_kv(char* __restrict__ Kb, char* __restrict__ Vb,
                                         const char* __restrict__ Kp,
                                         const char* __restrict__ Vt, int kv0,
                                         int tid) {
  const int wave = tid >> 6;
#pragma unroll
  for (int j = 0; j < 2; ++j) {
    int d = j * 256 + tid;  // chunk id 0..511
    int row = d >> 3, cc = d & 7;
    int gc = cc ^ (row & 7);
    const char* gk = Kp + (size_t)kv0 * 128 + row * 128 + gc * 16;
    async_copy16(Kb + (j * 256 + wave * 64) * 16, gk);
    const char* gv = Vt + (size_t)row * 4096 + (size_t)kv0 * 2 + gc * 16;
    async_copy16(Vb + (j * 256 + wave * 64) * 16, gv);
  }
}

__device__ __forceinline__ void qk_tile(floatx4 (&s)[2][4], const char* __restrict__ Kb,
                                        const short8 (&qf)[2][2], int lr, int lg) {
  floatx4 zero = {0.f, 0.f, 0.f, 0.f};
  const int x7 = lr & 7;
  __builtin_amdgcn_s_setprio(1);
#pragma unroll
  for (int nt = 0; nt < 4; ++nt) {
    const char* kr = Kb + (nt * 16 + lr) * 128;
    short8 kf0 = *(const short8*)(kr + ((lg ^ x7) * 16));
    short8 kf1 = *(const short8*)(kr + (((4 + lg) ^ x7) * 16));
#pragma unroll
    for (int qa = 0; qa < 2; ++qa) {
      floatx4 a = zero;
      a = __builtin_amdgcn_mfma_f32_16x16x32_bf16(kf0, qf[qa][0], a, 0, 0, 0);
      a = __builtin_amdgcn_mfma_f32_16x16x32_bf16(kf1, qf[qa][1], a, 0, 0, 0);
      s[qa][nt] = a;
    }
  }
  __builtin_amdgcn_s_setprio(0);
}

__device__ __forceinline__ void sm_pv(
    floatx4 (&s)[2][4], const char* __restrict__ Vb, char* __restrict__ PTw,
    int kv0, int q0, int lr, int lg, bool diag,
    float (&m_i)[2], float (&l_i)[2], floatx4 (&accO)[2][4]) {
  const int x7 = lr & 7;
  if (diag) {
#pragma unroll
    for (int qa = 0; qa < 2; ++qa) {
      const int q = q0 + qa * 16 + lr;
#pragma unroll
      for (int nt = 0; nt < 4; ++nt)
#pragma unroll
        for (int r = 0; r < 4; ++r) {
          int kvi = kv0 + nt * 16 + lg * 4 + r;
          if (kvi > q) s[qa][nt][r] = -1e30f;
        }
    }
  }

  float pmax[2];
#pragma unroll
  for (int qa = 0; qa < 2; ++qa) {
    float m0 = fmaxf(fmaxf(s[qa][0][0], s[qa][0][1]), fmaxf(s[qa][0][2], s[qa][0][3]));
    float m1 = fmaxf(fmaxf(s[qa][1][0], s[qa][1][1]), fmaxf(s[qa][1][2], s[qa][1][3]));
    float m2 = fmaxf(fmaxf(s[qa][2][0], s[qa][2][1]), fmaxf(s[qa][2][2], s[qa][2][3]));
    float m3 = fmaxf(fmaxf(s[qa][3][0], s[qa][3][1]), fmaxf(s[qa][3][2], s[qa][3][3]));
    pmax[qa] = fmaxf(fmaxf(m0, m1), fmaxf(m2, m3));
  }

  float g = fmaxf(pmax[0] - m_i[0], pmax[1] - m_i[1]);
  if (__any(g > 11.5f)) {
#pragma unroll
    for (int qa = 0; qa < 2; ++qa) {
      float mx = fmaxf(pmax[qa], __shfl_xor(pmax[qa], 16));
      mx = fmaxf(mx, __shfl_xor(mx, 32));
      float mnew = fmaxf(m_i[qa], mx);
      float scl = exp2f(m_i[qa] - mnew);
      m_i[qa] = mnew;
      l_i[qa] *= scl;
#pragma unroll
      for (int r = 0; r < 4; ++r) {
        float so = __shfl(scl, lg * 4 + r);
#pragma unroll
        for (int dt = 0; dt < 4; ++dt) accO[qa][dt][r] *= so;
      }
    }
  }

#pragma unroll
  for (int qa = 0; qa < 2; ++qa) {
    char* prow = PTw + (qa * 16 + lr) * 128;
#pragma unroll
    for (int nt = 0; nt < 4; ++nt) {
      float p0 = exp2f(s[qa][nt][0] - m_i[qa]);
      float p1 = exp2f(s[qa][nt][1] - m_i[qa]);
      float p2 = exp2f(s[qa][nt][2] - m_i[qa]);
      float p3 = exp2f(s[qa][nt][3] - m_i[qa]);
      l_i[qa] += (p0 + p1) + (p2 + p3);
      uint2 wv;
      wv.x = cvt_pk_bf16(p0, p1);
      wv.y = cvt_pk_bf16(p2, p3);
      *(uint2*)(prow + (((2 * nt + (lg >> 1)) ^ x7) * 16) + ((2 * lg) & 3) * 4) = wv;
    }
  }

  __builtin_amdgcn_s_setprio(1);
#pragma unroll
  for (int kk = 0; kk < 2; ++kk) {
    short8 pf0 = *(const short8*)(PTw + lr * 128 + (((4 * kk + lg) ^ x7) * 16));
    short8 pf1 = *(const short8*)(PTw + (16 + lr) * 128 + (((4 * kk + lg) ^ x7) * 16));
#pragma unroll
    for (int dt = 0; dt < 4; ++dt) {
      short8 vf = *(const short8*)(Vb + (dt * 16 + lr) * 128 + (((4 * kk + lg) ^ x7) * 16));
      accO[0][dt] = __builtin_amdgcn_mfma_f32_16x16x32_bf16(pf0, vf, accO[0][dt], 0, 0, 0);
      accO[1][dt] = __builtin_amdgcn_mfma_f32_16x16x32_bf16(pf1, vf, accO[1][dt], 0, 0, 0);
    }
  }
  __builtin_amdgcn_s_setprio(0);
}

__global__ __launch_bounds__(256, 2) void attn_fwd(
    const unsigned short* __restrict__ qb, const unsigned short* __restrict__ kb,
    const unsigned short* __restrict__ vtb, unsigned short* __restrict__ ob) {
  __shared__ __align__(16) char Kbuf[3][8192];
  __shared__ __align__(16) char Vbuf[3][8192];
  __shared__ __align__(16) char PTbuf[4][4096];

  const int bh = blockIdx.x * 8 + (blockIdx.y & 7);
  const int pr = blockIdx.y >> 3;  // 0..7

  const int tid = threadIdx.x;
  const int wave = tid >> 6, lane = tid & 63;
  const int lr = lane & 15, lg = lane >> 4;
  const unsigned short* Q = qb + (long)bh * 2048 * 64;
  const char* Kp = (const char*)(kb + (long)bh * 2048 * 64);
  const char* Vt = (const char*)(vtb + (long)bh * 64 * 2048);
  const int b = bh >> 4, h = bh & 15;
  char* PTw = PTbuf[wave];

  floatx4 zero = {0.f, 0.f, 0.f, 0.f};

#pragma unroll 1
  for (int half = 0; half < 2; ++half) {
    const int qt = half ? (15 - pr) : pr;  // 128-row q-tile index
    const int q0 = qt * 128 + wave * 32;
    const int nkv = 2 * qt + 2;  // always even

    short8 qf[2][2];
#pragma unroll
    for (int qa = 0; qa < 2; ++qa)
#pragma unroll
      for (int kk = 0; kk < 2; ++kk)
        qf[qa][kk] = *(const short8*)(Q + (q0 + qa * 16 + lr) * 64 + kk * 32 + lg * 8);

    floatx4 accO[2][4];
#pragma unroll
    for (int qa = 0; qa < 2; ++qa)
#pragma unroll
      for (int dt = 0; dt < 4; ++dt) accO[qa][dt] = zero;
    float m_i[2] = {-1e30f, -1e30f};
    float l_i[2] = {0.f, 0.f};

    // prologue: stage tiles 0,1; QK of tile 0
    stage_kv(Kbuf[0], Vbuf[0], Kp, Vt, 0, tid);
    __syncthreads();
    stage_kv(Kbuf[1], Vbuf[1], Kp, Vt, 64, tid);
    floatx4 sA[2][4], sB[2][4];
    qk_tile(sA, Kbuf[0], qf, lr, lg);

#pragma unroll 1
    for (int kv = 0; kv < nkv; kv += 2) {
      // even step: consume sA (tile kv), prefetch-compute sB (tile kv+1)
      __syncthreads();  // retires stage(kv+1)
      if (kv + 2 < nkv)
        stage_kv(Kbuf[(kv + 2) % 3], Vbuf[(kv + 2) % 3], Kp, Vt, (kv + 2) * 64, tid);
      qk_tile(sB, Kbuf[(kv + 1) % 3], qf, lr, lg);
      sm_pv(sA, Vbuf[kv % 3], PTw, kv * 64, q0, lr, lg, kv >= 2 * qt, m_i, l_i, accO);
      // odd step: consume sB (tile kv+1), prefetch-compute sA (tile kv+2)
      __syncthreads();  // retires stage(kv+2)
      if (kv + 3 < nkv)
        stage_kv(Kbuf[(kv + 3) % 3], Vbuf[(kv + 3) % 3], Kp, Vt, (kv + 3) * 64, tid);
      if (kv + 2 < nkv) qk_tile(sA, Kbuf[(kv + 2) % 3], qf, lr, lg);
      sm_pv(sB, Vbuf[(kv + 1) % 3], PTw, (kv + 1) * 64, q0, lr, lg, kv + 1 >= 2 * qt,
            m_i, l_i, accO);
    }

#pragma unroll
    for (int qa = 0; qa < 2; ++qa) {
      float lt = l_i[qa] + __shfl_xor(l_i[qa], 16);
      lt += __shfl_xor(lt, 32);
      float linv = 1.f / lt;
#pragma unroll
      for (int r = 0; r < 4; ++r) {
        float io = __shfl(linv, lg * 4 + r);
        int tq = q0 + qa * 16 + 4 * lg + r;
#pragma unroll
        for (int dt = 0; dt < 4; ++dt)
          ob[((long)b * 2048 + tq) * 1024 + h * 64 + dt * 16 + lr] =
              f2bf(accO[qa][dt][r] * io);
      }
    }
  }
}

// ---------------------------------------------------------------------------
extern "C" void kernel_launch(void* const* d_in, const int* in_sizes, int n_in,
                              void* d_out, int out_size, void* d_ws, size_t ws_size,
                              hipStream_t stream) {
  const float* x = (const float*)d_in[0];
  const float* bq = (const float*)d_in[2];
  const float* bk = (const float*)d_in[4];
  const float* bv = (const float*)d_in[6];
  const float* bo = (const float*)d_in[8];
  float* out = (float*)d_out;

  char* ws = (char*)d_ws;
  unsigned short* xb = (unsigned short*)(ws);                  // 16 MB  [8192][1024]
  unsigned short* wqkv = (unsigned short*)(ws + (16l << 20));  // 6 MB   [3072][1024]
  unsigned short* wob = (unsigned short*)(ws + (22l << 20));   // 2 MB   [1024][1024]
  unsigned short* qb = (unsigned short*)(ws + (24l << 20));    // 16 MB  [64][2048][64]
  unsigned short* kb = (unsigned short*)(ws + (40l << 20));    // 16 MB  [64][2048][64]
  unsigned short* vtb = (unsigned short*)(ws + (56l << 20));   // 16 MB  [64][64][2048]
  unsigned short* ob = (unsigned short*)(ws + (72l << 20));    // 16 MB  [8192][1024]

  f2ball_kernel<<<12288, 256, 0, stream>>>(
      x, xb, (const float*)d_in[1], (const float*)d_in[3], (const float*)d_in[5],
      (const float*)d_in[7], wqkv, wqkv + (1l << 20), wqkv + (2l << 20), wob);

  qkv_gemm<<<dim3(64, 24), 256, 0, stream>>>(xb, wqkv, bq, bk, bv, qb, kb, vtb);
  attn_fwd<<<dim3(8, 64), 256, 0, stream>>>(qb, kb, vtb, ob);
  out_gemm<<<dim3(64, 8), 256, 0, stream>>>(ob, wob, bo, out);
}

// Round 10
// 164.142 us; speedup vs baseline: 1.4157x; 1.0471x over previous
//
#include <hip/hip_runtime.h>
#include <stdint.h>

typedef __attribute__((ext_vector_type(8))) short short8;
typedef __attribute__((ext_vector_type(4))) short short4v;
typedef __attribute__((ext_vector_type(4))) float floatx4;

#define QSCALE 0.1803368801111f /* 0.125 * log2(e): S in log2 units */

__device__ __forceinline__ unsigned short f2bf(float f) {
  unsigned int u = __float_as_uint(f);
  unsigned int r = (u + 0x7FFFu + ((u >> 16) & 1u)) >> 16;  // RNE
  return (unsigned short)r;
}

__device__ __forceinline__ unsigned int cvt_pk_bf16(float lo, float hi) {
  unsigned int r;
  asm("v_cvt_pk_bf16_f32 %0, %1, %2" : "=v"(r) : "v"(lo), "v"(hi));
  return r;
}

__device__ __forceinline__ void async_copy16(void* lds, const void* g) {
  __builtin_amdgcn_global_load_lds(
      (const __attribute__((address_space(1))) unsigned int*)g,
      (__attribute__((address_space(3))) unsigned int*)lds, 16, 0, 0);
}

// ---------------------------------------------------------------------------
// ALL fp32 -> bf16 conversions in one launch.
// ---------------------------------------------------------------------------
__global__ __launch_bounds__(256) void f2ball_kernel(
    const float* __restrict__ x, unsigned short* __restrict__ xb,
    const float* __restrict__ w0, const float* __restrict__ w1,
    const float* __restrict__ w2, const float* __restrict__ w3,
    unsigned short* __restrict__ o0, unsigned short* __restrict__ o1,
    unsigned short* __restrict__ o2, unsigned short* __restrict__ o3) {
  const float* in;
  unsigned short* out;
  long i;
  if (blockIdx.x < 8192) {
    in = x;
    out = xb;
    i = (long)blockIdx.x * 256 + threadIdx.x;
  } else {
    int wb = blockIdx.x - 8192;
    int which = wb >> 10;
    in = (which == 0) ? w0 : (which == 1) ? w1 : (which == 2) ? w2 : w3;
    out = (which == 0) ? o0 : (which == 1) ? o1 : (which == 2) ? o2 : o3;
    i = (long)(wb & 1023) * 256 + threadIdx.x;
  }
  float4 v = ((const float4*)in)[i];
  short4v o;
  o[0] = (short)f2bf(v.x);
  o[1] = (short)f2bf(v.y);
  o[2] = (short)f2bf(v.z);
  o[3] = (short)f2bf(v.w);
  *(short4v*)(out + i * 4) = o;
}

// ---------------------------------------------------------------------------
// Double-buffered 2-phase GEMM mainloop (1 barrier per K-step).
// ---------------------------------------------------------------------------
__device__ __forceinline__ void gemm128_mainloop_db(
    const unsigned short* __restrict__ A, const unsigned short* __restrict__ Bt,
    int K, long brow, long bcol, unsigned short* As, unsigned short* Bs,
    floatx4 acc[4][4]) {
  const int tid = threadIdx.x;
  const int wave = tid >> 6;
  const int lane = tid & 63;
  const int wr = wave >> 1, wc = wave & 1;
  const int lr = lane & 15, lg = lane >> 4;

  const unsigned short* ga = A + (brow + (tid >> 2)) * (long)K + (tid & 3) * 8;
  const unsigned short* gb = Bt + (bcol + (tid >> 2)) * (long)K + (tid & 3) * 8;
  const int woff = wave * 512;
  const int a_off = (wr * 64 + lr) * 32 + lg * 8;
  const int b_off = (wc * 64 + lr) * 32 + lg * 8;

  async_copy16(As + woff, ga);
  async_copy16(As + woff + 2048, ga + (long)64 * K);
  async_copy16(Bs + woff, gb);
  async_copy16(Bs + woff + 2048, gb + (long)64 * K);
  ga += 32;
  gb += 32;
  __syncthreads();

  int buf = 0;
  for (int kt = 0; kt < K; kt += 32) {
    if (kt + 32 < K) {
      unsigned short* lA = As + (buf ^ 1) * 4096 + woff;
      unsigned short* lB = Bs + (buf ^ 1) * 4096 + woff;
      async_copy16(lA, ga);
      async_copy16(lA + 2048, ga + (long)64 * K);
      async_copy16(lB, gb);
      async_copy16(lB + 2048, gb + (long)64 * K);
      ga += 32;
      gb += 32;
    }
    const unsigned short* Ab = As + buf * 4096;
    const unsigned short* Bb = Bs + buf * 4096;
    short8 af[4], bf[4];
#pragma unroll
    for (int i = 0; i < 4; ++i) {
      af[i] = *(const short8*)(Ab + a_off + i * 512);
      bf[i] = *(const short8*)(Bb + b_off + i * 512);
    }
#pragma unroll
    for (int i = 0; i < 4; ++i)
#pragma unroll
      for (int j = 0; j < 4; ++j)
        acc[i][j] = __builtin_amdgcn_mfma_f32_16x16x32_bf16(af[i], bf[j], acc[i][j], 0, 0, 0);
    __syncthreads();
    buf ^= 1;
  }
}

// ---------------------------------------------------------------------------
// QKV projection. Q pre-scaled to log2 units. V-epilogue transposes the
// 128x128 tile through LDS so vt stores are 16B-contiguous in t.
// ---------------------------------------------------------------------------
__global__ __launch_bounds__(256, 4) void qkv_gemm(
    const unsigned short* __restrict__ xb, const unsigned short* __restrict__ wqkv,
    const float* __restrict__ bq, const float* __restrict__ bk,
    const float* __restrict__ bv, unsigned short* __restrict__ q_out,
    unsigned short* __restrict__ k_out, unsigned short* __restrict__ vt_out) {
  __shared__ __align__(16) unsigned short Sh[128 * 136];  // 34 KB
  unsigned short* As = Sh;
  unsigned short* Bs = Sh + 8192;
  floatx4 zero = {0.f, 0.f, 0.f, 0.f};
  floatx4 acc[4][4];
#pragma unroll
  for (int i = 0; i < 4; ++i)
#pragma unroll
    for (int j = 0; j < 4; ++j) acc[i][j] = zero;

  long brow = (long)blockIdx.x * 128;
  long bcol = (long)blockIdx.y * 128;
  gemm128_mainloop_db(xb, wqkv, 1024, brow, bcol, As, Bs, acc);

  const int wave = threadIdx.x >> 6, lane = threadIdx.x & 63;
  const int wr = wave >> 1, wc = wave & 1, lr = lane & 15, lg = lane >> 4;
  const int kind = (int)(bcol >> 10);
  const float* bias = (kind == 0) ? bq : (kind == 1 ? bk : bv);

  if (kind == 2) {
#pragma unroll
    for (int i = 0; i < 4; ++i)
#pragma unroll
      for (int j = 0; j < 4; ++j) {
        int n_local = wc * 64 + j * 16 + lr;
        int m_base = wr * 64 + i * 16 + lg * 4;
        float bsc = bias[(int)((bcol + n_local) & 1023)];
        short4v pk;
#pragma unroll
        for (int r = 0; r < 4; ++r) pk[r] = (short)f2bf(acc[i][j][r] + bsc);
        *(short4v*)(Sh + n_local * 136 + m_base) = pk;
      }
    __syncthreads();
    const int b = (int)(brow >> 11);
    const int t0 = (int)(brow & 2047);
    const int f0 = (int)(bcol - 2048);
#pragma unroll
    for (int p = 0; p < 8; ++p) {
      int c = p * 256 + threadIdx.x;
      int d_loc = c >> 4, tc = c & 15;
      short8 v = *(const short8*)(Sh + d_loc * 136 + tc * 8);
      int h = (f0 >> 6) + (d_loc >> 6);
      int d = d_loc & 63;
      *(short8*)(vt_out + ((long)((b * 16 + h) * 64 + d)) * 2048 + t0 + tc * 8) = v;
    }
  } else {
#pragma unroll
    for (int i = 0; i < 4; ++i)
#pragma unroll
      for (int j = 0; j < 4; ++j)
#pragma unroll
        for (int r = 0; r < 4; ++r) {
          int m = (int)brow + wr * 64 + i * 16 + lg * 4 + r;
          int n = (int)bcol + wc * 64 + j * 16 + lr;
          int f = n & 1023;
          float v = acc[i][j][r] + bias[f];
          if (kind == 0) v *= QSCALE;
          unsigned short o = f2bf(v);
          int h = f >> 6, d = f & 63;
          int bb = m >> 11, t = m & 2047;
          long bh = (long)(bb * 16 + h);
          if (kind == 0)
            q_out[(bh * 2048 + t) * 64 + d] = o;
          else
            k_out[(bh * 2048 + t) * 64 + d] = o;
        }
  }
}

// ---------------------------------------------------------------------------
// Output projection
// ---------------------------------------------------------------------------
__global__ __launch_bounds__(256, 4) void out_gemm(
    const unsigned short* __restrict__ ob, const unsigned short* __restrict__ wo,
    const float* __restrict__ bo, float* __restrict__ out) {
  __shared__ unsigned short As[2 * 128 * 32];
  __shared__ unsigned short Bs[2 * 128 * 32];
  floatx4 zero = {0.f, 0.f, 0.f, 0.f};
  floatx4 acc[4][4];
#pragma unroll
  for (int i = 0; i < 4; ++i)
#pragma unroll
    for (int j = 0; j < 4; ++j) acc[i][j] = zero;

  long brow = (long)blockIdx.x * 128;
  long bcol = (long)blockIdx.y * 128;
  gemm128_mainloop_db(ob, wo, 1024, brow, bcol, As, Bs, acc);

  const int wave = threadIdx.x >> 6, lane = threadIdx.x & 63;
  const int wr = wave >> 1, wc = wave & 1, lr = lane & 15, lg = lane >> 4;
#pragma unroll
  for (int i = 0; i < 4; ++i)
#pragma unroll
    for (int j = 0; j < 4; ++j)
#pragma unroll
      for (int r = 0; r < 4; ++r) {
        int m = (int)brow + wr * 64 + i * 16 + lg * 4 + r;
        int n = (int)bcol + wc * 64 + j * 16 + lr;
        out[(long)m * 1024 + n] = acc[i][j][r] + bo[n];
      }
}

// ---------------------------------------------------------------------------
// Flash attention v7: v5 double-buffer step, 48 KB LDS, 3 blocks/CU
// (launch_bounds(256,3)), UNPAIRED grid of 1024 blocks dispatched
// longest-first (id = (15-qt)*64 + bh; xcd = bh%8 keeps head locality).
// 32 q-rows/wave, log2-domain softmax, defer-max, per-lane l.
// ---------------------------------------------------------------------------
__device__ __forceinline__ void stage_kv(char* __restrict__ Kb, char* __restrict__ Vb,
                                         const char* __restrict__ Kp,
                                         const char* __restrict__ Vt, int kv0,
                                         int tid) {
  const int wave = tid >> 6;
#pragma unroll
  for (int j = 0; j < 2; ++j) {
    int d = j * 256 + tid;  // chunk id 0..511
    int row = d >> 3, cc = d & 7;
    int gc = cc ^ (row & 7);
    const char* gk = Kp + (size_t)kv0 * 128 + row * 128 + gc * 16;
    async_copy16(Kb + (j * 256 + wave * 64) * 16, gk);
    const char* gv = Vt + (size_t)row * 4096 + (size_t)kv0 * 2 + gc * 16;
    async_copy16(Vb + (j * 256 + wave * 64) * 16, gv);
  }
}

__device__ __forceinline__ void attn_step(
    const char* __restrict__ Kb, const char* __restrict__ Vb,
    char* __restrict__ PTw, const short8 (&qf)[2][2],
    int kv0, int q0, int lr, int lg, bool diag,
    float (&m_i)[2], float (&l_i)[2], floatx4 (&accO)[2][4]) {
  floatx4 zero = {0.f, 0.f, 0.f, 0.f};
  const int x7 = lr & 7;
  floatx4 s[2][4];
  __builtin_amdgcn_s_setprio(1);
#pragma unroll
  for (int nt = 0; nt < 4; ++nt) {
    const char* kr = Kb + (nt * 16 + lr) * 128;
    short8 kf0 = *(const short8*)(kr + ((lg ^ x7) * 16));
    short8 kf1 = *(const short8*)(kr + (((4 + lg) ^ x7) * 16));
#pragma unroll
    for (int qa = 0; qa < 2; ++qa) {
      floatx4 a = zero;
      a = __builtin_amdgcn_mfma_f32_16x16x32_bf16(kf0, qf[qa][0], a, 0, 0, 0);
      a = __builtin_amdgcn_mfma_f32_16x16x32_bf16(kf1, qf[qa][1], a, 0, 0, 0);
      s[qa][nt] = a;
    }
  }
  __builtin_amdgcn_s_setprio(0);

  if (diag) {
#pragma unroll
    for (int qa = 0; qa < 2; ++qa) {
      const int q = q0 + qa * 16 + lr;
#pragma unroll
      for (int nt = 0; nt < 4; ++nt)
#pragma unroll
        for (int r = 0; r < 4; ++r) {
          int kvi = kv0 + nt * 16 + lg * 4 + r;
          if (kvi > q) s[qa][nt][r] = -1e30f;
        }
    }
  }

  float pmax[2];
#pragma unroll
  for (int qa = 0; qa < 2; ++qa) {
    float m0 = fmaxf(fmaxf(s[qa][0][0], s[qa][0][1]), fmaxf(s[qa][0][2], s[qa][0][3]));
    float m1 = fmaxf(fmaxf(s[qa][1][0], s[qa][1][1]), fmaxf(s[qa][1][2], s[qa][1][3]));
    float m2 = fmaxf(fmaxf(s[qa][2][0], s[qa][2][1]), fmaxf(s[qa][2][2], s[qa][2][3]));
    float m3 = fmaxf(fmaxf(s[qa][3][0], s[qa][3][1]), fmaxf(s[qa][3][2], s[qa][3][3]));
    pmax[qa] = fmaxf(fmaxf(m0, m1), fmaxf(m2, m3));
  }

  float g = fmaxf(pmax[0] - m_i[0], pmax[1] - m_i[1]);
  if (__any(g > 11.5f)) {
#pragma unroll
    for (int qa = 0; qa < 2; ++qa) {
      float mx = fmaxf(pmax[qa], __shfl_xor(pmax[qa], 16));
      mx = fmaxf(mx, __shfl_xor(mx, 32));
      float mnew = fmaxf(m_i[qa], mx);
      float scl = exp2f(m_i[qa] - mnew);
      m_i[qa] = mnew;
      l_i[qa] *= scl;
#pragma unroll
      for (int r = 0; r < 4; ++r) {
        float so = __shfl(scl, lg * 4 + r);
#pragma unroll
        for (int dt = 0; dt < 4; ++dt) accO[qa][dt][r] *= so;
      }
    }
  }

#pragma unroll
  for (int qa = 0; qa < 2; ++qa) {
    char* prow = PTw + (qa * 16 + lr) * 128;
#pragma unroll
    for (int nt = 0; nt < 4; ++nt) {
      float p0 = exp2f(s[qa][nt][0] - m_i[qa]);
      float p1 = exp2f(s[qa][nt][1] - m_i[qa]);
      float p2 = exp2f(s[qa][nt][2] - m_i[qa]);
      float p3 = exp2f(s[qa][nt][3] - m_i[qa]);
      l_i[qa] += (p0 + p1) + (p2 + p3);
      uint2 wv;
      wv.x = cvt_pk_bf16(p0, p1);
      wv.y = cvt_pk_bf16(p2, p3);
      *(uint2*)(prow + (((2 * nt + (lg >> 1)) ^ x7) * 16) + ((2 * lg) & 3) * 4) = wv;
    }
  }

  __builtin_amdgcn_s_setprio(1);
#pragma unroll
  for (int kk = 0; kk < 2; ++kk) {
    short8 pf0 = *(const short8*)(PTw + lr * 128 + (((4 * kk + lg) ^ x7) * 16));
    short8 pf1 = *(const short8*)(PTw + (16 + lr) * 128 + (((4 * kk + lg) ^ x7) * 16));
#pragma unroll
    for (int dt = 0; dt < 4; ++dt) {
      short8 vf = *(const short8*)(Vb + (dt * 16 + lr) * 128 + (((4 * kk + lg) ^ x7) * 16));
      accO[0][dt] = __builtin_amdgcn_mfma_f32_16x16x32_bf16(pf0, vf, accO[0][dt], 0, 0, 0);
      accO[1][dt] = __builtin_amdgcn_mfma_f32_16x16x32_bf16(pf1, vf, accO[1][dt], 0, 0, 0);
    }
  }
  __builtin_amdgcn_s_setprio(0);
}

__global__ __launch_bounds__(256, 3) void attn_fwd(
    const unsigned short* __restrict__ qb, const unsigned short* __restrict__ kb,
    const unsigned short* __restrict__ vtb, unsigned short* __restrict__ ob) {
  __shared__ __align__(16) char Kbuf[2][8192];
  __shared__ __align__(16) char Vbuf[2][8192];
  __shared__ __align__(16) char PTbuf[4][4096];

  // id = (15-qt)*64 + bh : longest blocks dispatch first (LPT), and
  // xcd = id%8 = bh%8 keeps all of a head's q-tiles on one XCD.
  const int id = blockIdx.x;
  const int qt = 15 - (id >> 6);
  const int bh = id & 63;

  const int tid = threadIdx.x;
  const int wave = tid >> 6, lane = tid & 63;
  const int lr = lane & 15, lg = lane >> 4;
  const unsigned short* Q = qb + (long)bh * 2048 * 64;
  const char* Kp = (const char*)(kb + (long)bh * 2048 * 64);
  const char* Vt = (const char*)(vtb + (long)bh * 64 * 2048);
  const int b = bh >> 4, h = bh & 15;
  char* PTw = PTbuf[wave];

  floatx4 zero = {0.f, 0.f, 0.f, 0.f};

  const int q0 = qt * 128 + wave * 32;
  const int nkv = 2 * qt + 2;

  short8 qf[2][2];
#pragma unroll
  for (int qa = 0; qa < 2; ++qa)
#pragma unroll
    for (int kk = 0; kk < 2; ++kk)
      qf[qa][kk] = *(const short8*)(Q + (q0 + qa * 16 + lr) * 64 + kk * 32 + lg * 8);

  floatx4 accO[2][4];
#pragma unroll
  for (int qa = 0; qa < 2; ++qa)
#pragma unroll
    for (int dt = 0; dt < 4; ++dt) accO[qa][dt] = zero;
  float m_i[2] = {-1e30f, -1e30f};
  float l_i[2] = {0.f, 0.f};

  stage_kv(Kbuf[0], Vbuf[0], Kp, Vt, 0, tid);
  __syncthreads();
#pragma unroll 1
  for (int kv = 0; kv < nkv; ++kv) {
    if (kv + 1 < nkv)
      stage_kv(Kbuf[(kv + 1) & 1], Vbuf[(kv + 1) & 1], Kp, Vt, (kv + 1) * 64, tid);
    attn_step(Kbuf[kv & 1], Vbuf[kv & 1], PTw, qf, kv * 64, q0, lr, lg,
              kv >= 2 * qt, m_i, l_i, accO);
    __syncthreads();
  }

#pragma unroll
  for (int qa = 0; qa < 2; ++qa) {
    float lt = l_i[qa] + __shfl_xor(l_i[qa], 16);
    lt += __shfl_xor(lt, 32);
    float linv = 1.f / lt;
#pragma unroll
    for (int r = 0; r < 4; ++r) {
      float io = __shfl(linv, lg * 4 + r);
      int tq = q0 + qa * 16 + 4 * lg + r;
#pragma unroll
      for (int dt = 0; dt < 4; ++dt)
        ob[((long)b * 2048 + tq) * 1024 + h * 64 + dt * 16 + lr] =
            f2bf(accO[qa][dt][r] * io);
    }
  }
}

// ---------------------------------------------------------------------------
extern "C" void kernel_launch(void* const* d_in, const int* in_sizes, int n_in,
                              void* d_out, int out_size, void* d_ws, size_t ws_size,
                              hipStream_t stream) {
  const float* x = (const float*)d_in[0];
  const float* bq = (const float*)d_in[2];
  const float* bk = (const float*)d_in[4];
  const float* bv = (const float*)d_in[6];
  const float* bo = (const float*)d_in[8];
  float* out = (float*)d_out;

  char* ws = (char*)d_ws;
  unsigned short* xb = (unsigned short*)(ws);                  // 16 MB  [8192][1024]
  unsigned short* wqkv = (unsigned short*)(ws + (16l << 20));  // 6 MB   [3072][1024]
  unsigned short* wob = (unsigned short*)(ws + (22l << 20));   // 2 MB   [1024][1024]
  unsigned short* qb = (unsigned short*)(ws + (24l << 20));    // 16 MB  [64][2048][64]
  unsigned short* kb = (unsigned short*)(ws + (40l << 20));    // 16 MB  [64][2048][64]
  unsigned short* vtb = (unsigned short*)(ws + (56l << 20));   // 16 MB  [64][64][2048]
  unsigned short* ob = (unsigned short*)(ws + (72l << 20));    // 16 MB  [8192][1024]

  f2ball_kernel<<<12288, 256, 0, stream>>>(
      x, xb, (const float*)d_in[1], (const float*)d_in[3], (const float*)d_in[5],
      (const float*)d_in[7], wqkv, wqkv + (1l << 20), wqkv + (2l << 20), wob);

  qkv_gemm<<<dim3(64, 24), 256, 0, stream>>>(xb, wqkv, bq, bk, bv, qb, kb, vtb);
  attn_fwd<<<1024, 256, 0, stream>>>(qb, kb, vtb, ob);
  out_gemm<<<dim3(64, 8), 256, 0, stream>>>(ob, wob, bo, out);
}